// Round 2
// baseline (2202.446 us; speedup 1.0000x reference)
//
#include <hip/hip_runtime.h>

// Channel attention (XCA windowed) for MI355X / gfx950.
// Shapes: b=2, C=384, H=W=224, heads=8, d=48, ps=7, nh=nw=32, windows=1024, s=49.
// Pipeline: [k_cvt] weights->bf16 | [k_gemm<1,0>] qkv 1x1 (MFMA) -> bf16 NCHW
//           [k_dw] depthwise 3x3 -> bf16 window-major [b][win][1152][49]
//           [k_attn] per-(b,win,head): l2norm+temp folded into logits, S=q k^T (MFMA),
//                    softmax rows, O=P v (MFMA) -> bf16 NCHW
//           [k_gemm<0,1>] proj 1x1 (MFMA) -> fp32 d_out

#define NB     2
#define CC     384
#define C3     1152
#define HH     224
#define WW2    224
#define HW     50176
#define NHEADS 8
#define DD     48
#define PSZ    7
#define NWINS  1024
#define SS     49

typedef unsigned int  u32;
typedef unsigned short u16;
typedef __bf16 bf16x8 __attribute__((ext_vector_type(8)));
typedef float  f32x4  __attribute__((ext_vector_type(4)));

__device__ __forceinline__ u16 f2bf(float f){
  union { float f; u32 u; } v; v.f = f;
  u32 r = v.u + 0x7FFFu + ((v.u >> 16) & 1u);   // round-to-nearest-even
  return (u16)(r >> 16);
}
__device__ __forceinline__ float bf2f(u16 h){
  union { u32 u; float f; } v; v.u = ((u32)h) << 16;
  return v.f;
}

// XOR swizzle for LDS tiles with 64-ushort (128 B) rows: byte ^= ((row&7)<<4).
// Keeps 16-B alignment for 8-element (16 B) vector reads; kills the 32-way
// same-bank conflict of the raw 128 B row stride (cdna guide G4 / m214).
__device__ __forceinline__ int swz(int row, int col){
  return row*64 + ((((col << 1) ^ ((row & 7) << 4))) >> 1);
}

// ---------------- weight conversion ----------------
__global__ void k_cvt(const float* __restrict__ qw, const float* __restrict__ pw,
                      u16* __restrict__ qwb, u16* __restrict__ pwb){
  int i = blockIdx.x * 256 + threadIdx.x;
  if (i < C3*CC) qwb[i] = f2bf(qw[i]);
  if (i < CC*CC) pwb[i] = f2bf(pw[i]);
}

// ---------------- sentinel (ws too small) ----------------
__global__ void k_sentinel(float* __restrict__ out, int n){
  int i = blockIdx.x * 256 + threadIdx.x;
  if (i < n) out[i] = 12345.0f;
}

// ---------------- 1x1-conv GEMM ----------------
// C[b][m][p] = sum_k A[m][k] * B[b][k][p];  M = gridDim.x*128, K=384, N=50176.
// A: bf16 row-major [M][384]. B: fp32 or bf16 [b][384][50176]. 128x128 tile, BK=32.
// 4 waves 2x2; per-wave 64x64 = 4x4 frags of 16x16x32 bf16 MFMA.
template<int B_F32, int OUT_F32>
__global__ __launch_bounds__(256) void k_gemm(const u16* __restrict__ A,
    const void* __restrict__ Bsrc, void* __restrict__ Cdst){
  __shared__ u16 As[128*32];   // [m][k] row-major
  __shared__ u16 Bs[128*32];   // [n][k] (transposed at staging)
  const int m0 = blockIdx.x * 128, n0 = blockIdx.y * 128, b = blockIdx.z;
  const int M  = gridDim.x * 128;
  const int tid = threadIdx.x, lane = tid & 63, wv = tid >> 6;
  const int wm = (wv & 1) * 64, wn = (wv >> 1) * 64;
  const int lr = lane & 15, lg = lane >> 4;

  f32x4 acc[4][4];
  #pragma unroll
  for (int i=0;i<4;++i)
    #pragma unroll
    for (int j=0;j<4;++j) acc[i][j] = {0.f,0.f,0.f,0.f};

  for (int kk=0; kk<12; ++kk){
    const int k0 = kk*32;
    __syncthreads();
    // ---- stage A: 512 16-B chunks, 2 per thread (coalesced dwordx4) ----
    #pragma unroll
    for (int i=0;i<2;++i){
      int chunk = i*256 + tid;
      int row = chunk >> 2, c4 = chunk & 3;
      const uint4 v = *(const uint4*)(A + (size_t)(m0+row)*CC + k0 + c4*8);
      *(uint4*)(As + chunk*8) = v;               // chunk*8 = row*32 + c4*8
    }
    // ---- stage B transposed: thread owns k-pair (k2,k2+1), 8 n's stride 16 ----
    {
      const int k2 = (tid >> 4) * 2, nl = tid & 15;
      if (B_F32){
        const float* X = (const float*)Bsrc + (size_t)b*CC*HW + (size_t)(k0+k2)*HW + n0;
        #pragma unroll
        for (int j=0;j<8;++j){
          int n = nl + j*16;
          u32 p = (u32)f2bf(X[n]) | ((u32)f2bf(X[n+HW]) << 16);
          *(u32*)(Bs + n*32 + k2) = p;
        }
      } else {
        const u16* X = (const u16*)Bsrc + (size_t)b*CC*HW + (size_t)(k0+k2)*HW + n0;
        #pragma unroll
        for (int j=0;j<8;++j){
          int n = nl + j*16;
          u32 p = (u32)X[n] | ((u32)X[n+HW] << 16);
          *(u32*)(Bs + n*32 + k2) = p;
        }
      }
    }
    __syncthreads();
    // ---- compute: 8 ds_read_b128 + 16 MFMA ----
    bf16x8 af[4], bfr[4];
    #pragma unroll
    for (int i=0;i<4;++i) af[i]  = *(const bf16x8*)(As + (wm + i*16 + lr)*32 + lg*8);
    #pragma unroll
    for (int j=0;j<4;++j) bfr[j] = *(const bf16x8*)(Bs + (wn + j*16 + lr)*32 + lg*8);
    #pragma unroll
    for (int i=0;i<4;++i)
      #pragma unroll
      for (int j=0;j<4;++j)
        acc[i][j] = __builtin_amdgcn_mfma_f32_16x16x32_bf16(af[i], bfr[j], acc[i][j], 0, 0, 0);
  }
  // ---- epilogue: C frag col=lane&15, row=(lane>>4)*4+reg (m89) ----
  #pragma unroll
  for (int i=0;i<4;++i){
    #pragma unroll
    for (int j=0;j<4;++j){
      const int row = m0 + wm + i*16 + lg*4;
      const int col = n0 + wn + j*16 + lr;
      if (OUT_F32){
        float* Cp = (float*)Cdst + (size_t)b*M*HW;
        #pragma unroll
        for (int r=0;r<4;++r) Cp[(size_t)(row+r)*HW + col] = acc[i][j][r];
      } else {
        u16* Cp = (u16*)Cdst + (size_t)b*M*HW;
        #pragma unroll
        for (int r=0;r<4;++r) Cp[(size_t)(row+r)*HW + col] = f2bf(acc[i][j][r]);
      }
    }
  }
}

// ---------------- depthwise 3x3, SAME ----------------
// One thread = one (b,win,o,pi) -> 7 outputs (one window row), written to
// window-major layout [b][win][o][pi][pj] (contiguous per (win,o)).
__global__ __launch_bounds__(256) void k_dw(const u16* __restrict__ qkv,
    const float* __restrict__ dww, u16* __restrict__ qkv2){
  long tid = (long)blockIdx.x * 256 + threadIdx.x;
  if (tid >= (long)NB*NWINS*C3*PSZ) return;
  int pi = (int)(tid % 7);   long t1 = tid / 7;
  int o  = (int)(t1 % C3);   long t2 = t1 / C3;
  int win= (int)(t2 % NWINS);
  int b  = (int)(t2 / NWINS);
  int wy = win >> 5, wx = win & 31;
  int y0 = wy*PSZ + pi;
  int xbase = wx*PSZ;

  float wk[9];
  #pragma unroll
  for (int i=0;i<9;++i) wk[i] = dww[o*9 + i];

  float r[3][9];
  const u16* src = qkv + (size_t)(b*C3 + o) * HW;
  #pragma unroll
  for (int dy=0;dy<3;++dy){
    int y = y0 + dy - 1;
    bool yok = (y >= 0) & (y < HH);
    #pragma unroll
    for (int i=0;i<9;++i){
      int xx = xbase + i - 1;
      bool ok = yok & (xx >= 0) & (xx < WW2);
      r[dy][i] = ok ? bf2f(src[(size_t)y*WW2 + xx]) : 0.f;
    }
  }
  size_t obase = (((size_t)(b*NWINS + win)*C3 + o)*PSZ + pi)*PSZ;
  #pragma unroll
  for (int pj=0;pj<7;++pj){
    float s = 0.f;
    #pragma unroll
    for (int ky=0;ky<3;++ky)
      #pragma unroll
      for (int kx=0;kx<3;++kx)
        s += wk[ky*3+kx] * r[ky][pj+kx];
    qkv2[obase + pj] = f2bf(s);
  }
}

// ---------------- windowed channel attention ----------------
// Block = (head, win, b), 256 threads / 4 waves.
// S[d][e] = (q[d].k[e]) * invq[d] * invk[e]  (temp folded into invq),
// softmax over e, O = P v. K-dims padded to 64 with zeros in LDS.
__global__ __launch_bounds__(256) void k_attn(const u16* __restrict__ qkv2,
    const float* __restrict__ temp, u16* __restrict__ aout){
  const int h = blockIdx.x, win = blockIdx.y, b = blockIdx.z;
  const int tid = threadIdx.x, lane = tid & 63, wv = tid >> 6;
  const int lr = lane & 15, lg = lane >> 4;

  __shared__ u16 q_s[48*64], k_s[48*64], v_t[64*64], p_s[48*64];
  __shared__ float smat[48*48];
  __shared__ float invq[48], invk[48];

  // zero all padded tiles (pad regions must be 0, not garbage/NaN, for MFMA)
  for (int i=tid; i<48*32; i+=256){ ((u32*)q_s)[i]=0u; ((u32*)k_s)[i]=0u; ((u32*)p_s)[i]=0u; }
  for (int i=tid; i<64*32; i+=256) ((u32*)v_t)[i]=0u;
  __syncthreads();

  const u16* base = qkv2 + (size_t)(b*NWINS + win) * (C3*SS);
  const u16* qsrc = base + (h*DD)*SS;
  const u16* ksrc = base + (CC + h*DD)*SS;
  const u16* vsrc = base + (2*CC + h*DD)*SS;
  for (int i=tid; i<DD*SS; i+=256){
    int dc = i / SS, s = i - dc*SS;
    q_s[swz(dc,s)] = qsrc[i];
    k_s[swz(dc,s)] = ksrc[i];
    v_t[swz(s,dc)] = vsrc[i];      // transposed: v_t[s][e]
  }
  __syncthreads();

  // l2-norm factors: threads 0..47 -> q rows, threads 48..95 -> k rows.
  // (round-1 bug: `tid & 47` is NOT a modulo-48 mask -> invk[16..31] was
  //  uninitialized garbage. Use explicit subtraction.)
  if (tid < 96){
    int rr = (tid < 48) ? tid : (tid - 48);
    const u16* a = (tid < 48) ? q_s : k_s;
    float sum = 0.f;
    for (int s=0;s<SS;++s){ float v = bf2f(a[swz(rr,s)]); sum += v*v; }
    float inv = 1.f / fmaxf(sqrtf(sum), 1e-12f);
    if (tid < 48) invq[rr] = inv * temp[h]; else invk[rr] = inv;
  }
  __syncthreads();

  // S = q k^T : 3x3 tiles of 16x16, K=64 (49 real + zero pad)
  for (int t = wv; t < 9; t += 4){
    int ti = t/3, tj = t - ti*3;
    f32x4 c = {0.f,0.f,0.f,0.f};
    #pragma unroll
    for (int ks=0; ks<2; ++ks){
      bf16x8 a  = *(const bf16x8*)(q_s + swz(ti*16+lr, ks*32 + lg*8));
      bf16x8 bb = *(const bf16x8*)(k_s + swz(tj*16+lr, ks*32 + lg*8));
      c = __builtin_amdgcn_mfma_f32_16x16x32_bf16(a, bb, c, 0,0,0);
    }
    #pragma unroll
    for (int r=0;r<4;++r) smat[(ti*16 + lg*4 + r)*48 + tj*16 + lr] = c[r];
  }
  __syncthreads();

  // softmax rows (thread t<48 owns row t; scale by invq/invk here)
  if (tid < 48){
    const int row = tid; const float iq = invq[row];
    float m = -1e30f;
    for (int e=0;e<48;++e) m = fmaxf(m, smat[row*48+e]*iq*invk[e]);
    float sum = 0.f;
    for (int e=0;e<48;++e){
      float p = __expf(smat[row*48+e]*iq*invk[e] - m);
      smat[row*48+e] = p; sum += p;
    }
    float is = 1.f / sum;
    for (int e=0;e<48;++e) p_s[swz(row,e)] = f2bf(smat[row*48+e]*is);
  }
  __syncthreads();

  // O = P v : 3x4 tiles (d x s), K=64 (48 real e + zero pad)
  const int wy = win >> 5, wx = win & 31;
  for (int t = wv; t < 12; t += 4){
    int ti = t >> 2, tj = t & 3;
    f32x4 c = {0.f,0.f,0.f,0.f};
    #pragma unroll
    for (int ks=0; ks<2; ++ks){
      bf16x8 a  = *(const bf16x8*)(p_s + swz(ti*16+lr, ks*32 + lg*8));
      bf16x8 bb = *(const bf16x8*)(v_t + swz(tj*16+lr, ks*32 + lg*8));
      c = __builtin_amdgcn_mfma_f32_16x16x32_bf16(a, bb, c, 0,0,0);
    }
    int scol = tj*16 + lr;
    if (scol < SS){
      int pi = scol / PSZ, pj = scol - pi*PSZ;
      size_t px = (size_t)(wy*PSZ + pi)*WW2 + wx*PSZ + pj;
      #pragma unroll
      for (int r=0;r<4;++r){
        int d = ti*16 + lg*4 + r;
        aout[(size_t)(b*CC + h*DD + d)*HW + px] = f2bf(c[r]);
      }
    }
  }
}

// ---------------- launch ----------------
extern "C" void kernel_launch(void* const* d_in, const int* in_sizes, int n_in,
                              void* d_out, int out_size, void* d_ws, size_t ws_size,
                              hipStream_t stream) {
  const float* x     = (const float*)d_in[0];
  const float* qkvw  = (const float*)d_in[1];
  const float* dww   = (const float*)d_in[2];
  const float* temp  = (const float*)d_in[3];
  const float* projw = (const float*)d_in[4];
  float* out = (float*)d_out;

  // ws layout (bytes)
  const size_t SZ_QKV  = (size_t)NB*C3*HW*2;          // 231,211,008
  const size_t OFF_QKV2 = SZ_QKV;
  const size_t OFF_AO   = OFF_QKV2 + SZ_QKV;          // 462,422,016
  const size_t OFF_W1   = OFF_AO + (size_t)NB*CC*HW*2;// 539,492,352
  const size_t OFF_W2   = OFF_W1 + (size_t)C3*CC*2;   // 540,377,088
  const size_t NEEDED   = OFF_W2 + (size_t)CC*CC*2;   // 540,672,000

  if (ws_size < NEEDED){
    // distinguishable failure signature (absmax ~12345) instead of OOB corruption
    k_sentinel<<<(out_size + 255)/256, 256, 0, stream>>>(out, out_size);
    return;
  }
  char* ws = (char*)d_ws;
  u16* qkv  = (u16*)ws;
  u16* qkv2 = (u16*)(ws + OFF_QKV2);
  u16* ao   = (u16*)(ws + OFF_AO);
  u16* qwb  = (u16*)(ws + OFF_W1);
  u16* pwb  = (u16*)(ws + OFF_W2);

  k_cvt<<<dim3((C3*CC)/256), 256, 0, stream>>>(qkvw, projw, qwb, pwb);
  k_gemm<1,0><<<dim3(9,392,2), 256, 0, stream>>>(qwb, x, qkv);
  k_dw<<<dim3((NB*NWINS*C3*PSZ)/256), 256, 0, stream>>>(qkv, dww, qkv2);
  k_attn<<<dim3(NHEADS, NWINS, NB), 256, 0, stream>>>(qkv2, temp, ao);
  k_gemm<0,1><<<dim3(3,392,2), 256, 0, stream>>>(pwb, ao, out);
}

// Round 3
// 987.534 us; speedup vs baseline: 2.2302x; 2.2302x over previous
//
#include <hip/hip_runtime.h>

// Channel attention (XCA windowed) for MI355X / gfx950.
// Shapes: b=2, C=384, H=W=224, heads=8, d=48, ps=7, nh=nw=32, windows=1024, s=49.
// Pipeline: [k_cvt] weights->bf16 | [k_gemm<1,0>] qkv 1x1 (MFMA) -> bf16 NCHW
//           [k_dw] depthwise 3x3, LDS-staged stripes -> bf16 window-major [b][win][1152][49]
//           [k_attn] per-(b,win,head): l2norm+temp folded into logits, S=q k^T (MFMA),
//                    softmax rows, O=P v (MFMA) -> bf16 NCHW
//           [k_gemm<0,1>] proj 1x1 (MFMA) -> fp32 d_out

#define NB     2
#define CC     384
#define C3     1152
#define HH     224
#define WW2    224
#define HW     50176
#define NHEADS 8
#define DD     48
#define PSZ    7
#define NWINS  1024
#define SS     49

typedef unsigned int  u32;
typedef unsigned short u16;
typedef __bf16 bf16x8 __attribute__((ext_vector_type(8)));
typedef float  f32x4  __attribute__((ext_vector_type(4)));

__device__ __forceinline__ u16 f2bf(float f){
  union { float f; u32 u; } v; v.f = f;
  u32 r = v.u + 0x7FFFu + ((v.u >> 16) & 1u);   // round-to-nearest-even
  return (u16)(r >> 16);
}
__device__ __forceinline__ float bf2f(u16 h){
  union { u32 u; float f; } v; v.u = ((u32)h) << 16;
  return v.f;
}

// XOR swizzle for LDS tiles with 64-ushort (128 B) rows: byte ^= ((row&7)<<4).
__device__ __forceinline__ int swz(int row, int col){
  return row*64 + ((((col << 1) ^ ((row & 7) << 4))) >> 1);
}

// ---------------- weight conversion ----------------
__global__ void k_cvt(const float* __restrict__ qw, const float* __restrict__ pw,
                      u16* __restrict__ qwb, u16* __restrict__ pwb){
  int i = blockIdx.x * 256 + threadIdx.x;
  if (i < C3*CC) qwb[i] = f2bf(qw[i]);
  if (i < CC*CC) pwb[i] = f2bf(pw[i]);
}

// ---------------- sentinel (ws too small) ----------------
__global__ void k_sentinel(float* __restrict__ out, int n){
  int i = blockIdx.x * 256 + threadIdx.x;
  if (i < n) out[i] = 12345.0f;
}

// ---------------- 1x1-conv GEMM ----------------
// C[b][m][p] = sum_k A[m][k] * B[b][k][p];  M = gridDim.x*128, K=384, N=50176.
// A: bf16 row-major [M][384]. B: fp32 or bf16 [b][384][50176]. 128x128 tile, BK=32.
template<int B_F32, int OUT_F32>
__global__ __launch_bounds__(256) void k_gemm(const u16* __restrict__ A,
    const void* __restrict__ Bsrc, void* __restrict__ Cdst){
  __shared__ u16 As[128*32];   // [m][k] row-major
  __shared__ u16 Bs[128*32];   // [n][k] (transposed at staging)
  const int m0 = blockIdx.x * 128, n0 = blockIdx.y * 128, b = blockIdx.z;
  const int M  = gridDim.x * 128;
  const int tid = threadIdx.x, lane = tid & 63, wv = tid >> 6;
  const int wm = (wv & 1) * 64, wn = (wv >> 1) * 64;
  const int lr = lane & 15, lg = lane >> 4;

  f32x4 acc[4][4];
  #pragma unroll
  for (int i=0;i<4;++i)
    #pragma unroll
    for (int j=0;j<4;++j) acc[i][j] = {0.f,0.f,0.f,0.f};

  for (int kk=0; kk<12; ++kk){
    const int k0 = kk*32;
    __syncthreads();
    // ---- stage A: 512 16-B chunks, 2 per thread (coalesced dwordx4) ----
    #pragma unroll
    for (int i=0;i<2;++i){
      int chunk = i*256 + tid;
      int row = chunk >> 2, c4 = chunk & 3;
      const uint4 v = *(const uint4*)(A + (size_t)(m0+row)*CC + k0 + c4*8);
      *(uint4*)(As + chunk*8) = v;               // chunk*8 = row*32 + c4*8
    }
    // ---- stage B transposed: thread owns k-pair (k2,k2+1), 8 n's stride 16 ----
    {
      const int k2 = (tid >> 4) * 2, nl = tid & 15;
      if (B_F32){
        const float* X = (const float*)Bsrc + (size_t)b*CC*HW + (size_t)(k0+k2)*HW + n0;
        #pragma unroll
        for (int j=0;j<8;++j){
          int n = nl + j*16;
          u32 p = (u32)f2bf(X[n]) | ((u32)f2bf(X[n+HW]) << 16);
          *(u32*)(Bs + n*32 + k2) = p;
        }
      } else {
        const u16* X = (const u16*)Bsrc + (size_t)b*CC*HW + (size_t)(k0+k2)*HW + n0;
        #pragma unroll
        for (int j=0;j<8;++j){
          int n = nl + j*16;
          u32 p = (u32)X[n] | ((u32)X[n+HW] << 16);
          *(u32*)(Bs + n*32 + k2) = p;
        }
      }
    }
    __syncthreads();
    // ---- compute: 8 ds_read_b128 + 16 MFMA ----
    bf16x8 af[4], bfr[4];
    #pragma unroll
    for (int i=0;i<4;++i) af[i]  = *(const bf16x8*)(As + (wm + i*16 + lr)*32 + lg*8);
    #pragma unroll
    for (int j=0;j<4;++j) bfr[j] = *(const bf16x8*)(Bs + (wn + j*16 + lr)*32 + lg*8);
    #pragma unroll
    for (int i=0;i<4;++i)
      #pragma unroll
      for (int j=0;j<4;++j)
        acc[i][j] = __builtin_amdgcn_mfma_f32_16x16x32_bf16(af[i], bfr[j], acc[i][j], 0, 0, 0);
  }
  // ---- epilogue: C frag col=lane&15, row=(lane>>4)*4+reg (m89) ----
  #pragma unroll
  for (int i=0;i<4;++i){
    #pragma unroll
    for (int j=0;j<4;++j){
      const int row = m0 + wm + i*16 + lg*4;
      const int col = n0 + wn + j*16 + lr;
      if (OUT_F32){
        float* Cp = (float*)Cdst + (size_t)b*M*HW;
        #pragma unroll
        for (int r=0;r<4;++r) Cp[(size_t)(row+r)*HW + col] = acc[i][j][r];
      } else {
        u16* Cp = (u16*)Cdst + (size_t)b*M*HW;
        #pragma unroll
        for (int r=0;r<4;++r) Cp[(size_t)(row+r)*HW + col] = f2bf(acc[i][j][r]);
      }
    }
  }
}

// ---------------- depthwise 3x3, SAME — LDS-staged stripe version ----------------
// Block = (wy, o, b): 7 output rows x 224 cols of one channel.
// Stage 9 input rows (contiguous 4032-B span in NCHW) + halo cols into LDS,
// then thread t<224 = (wx=t/7, pi=t%7) computes 7 outputs (one window row),
// writing a contiguous 14-B chunk; 7 consecutive lanes cover 98 B contiguous.
// Round-2 profile: old per-thread scalar-gather version fetched 1.67 GB
// (7.2x amplification, 128-B granule x 9 scattered row-reads) -> 1584 us.
#define DW_LD  226   // 224 + 2 halo cols, u16 units
__global__ __launch_bounds__(256) void k_dw(const u16* __restrict__ qkv,
    const float* __restrict__ dww, u16* __restrict__ qkv2){
  const int wy = blockIdx.x, o = blockIdx.y, b = blockIdx.z;
  const int tid = threadIdx.x;
  __shared__ u16 lds[9*DW_LD];

  const u16* src = qkv + (size_t)(b*C3 + o) * HW;
  const int y0 = wy*PSZ - 1;

  // stage: 9 rows x 112 u32 (224 bf16) each, coalesced; zero out-of-range rows
  for (int i = tid; i < 9*112; i += 256){
    int r = i / 112, c2 = i - r*112;          // c2: u32 index within row
    int y = y0 + r;
    u32 v = 0u;
    if (y >= 0 && y < HH) v = *(const u32*)(src + (size_t)y*WW2 + c2*2);
    lds[r*DW_LD + 1 + c2*2]     = (u16)(v & 0xffffu);
    lds[r*DW_LD + 1 + c2*2 + 1] = (u16)(v >> 16);
  }
  if (tid < 18){ int r = tid >> 1; lds[r*DW_LD + (tid & 1)*225] = 0; }  // col halos
  __syncthreads();

  if (tid < 224){
    // weights are block-uniform -> scalar loads
    float wk[9];
    #pragma unroll
    for (int i=0;i<9;++i) wk[i] = dww[o*9 + i];

    const int wx = tid / PSZ, pi = tid - wx*PSZ;
    const int xb = wx * PSZ;                  // output cols xb..xb+6
    // inputs: rows pi..pi+2 (lds rows), cols xb..xb+8 (halo offset folded)
    float row0[9], row1[9], row2[9];
    #pragma unroll
    for (int c=0;c<9;++c){
      row0[c] = bf2f(lds[(pi+0)*DW_LD + xb + c]);
      row1[c] = bf2f(lds[(pi+1)*DW_LD + xb + c]);
      row2[c] = bf2f(lds[(pi+2)*DW_LD + xb + c]);
    }
    u16* dst = qkv2 + (((size_t)(b*NWINS + wy*32 + wx)*C3 + o)*SS) + pi*PSZ;
    #pragma unroll
    for (int pj=0;pj<PSZ;++pj){
      float s = 0.f;
      #pragma unroll
      for (int kx=0;kx<3;++kx){
        s += wk[0*3+kx]*row0[pj+kx];
        s += wk[1*3+kx]*row1[pj+kx];
        s += wk[2*3+kx]*row2[pj+kx];
      }
      dst[pj] = f2bf(s);
    }
  }
}

// ---------------- windowed channel attention ----------------
__global__ __launch_bounds__(256) void k_attn(const u16* __restrict__ qkv2,
    const float* __restrict__ temp, u16* __restrict__ aout){
  const int h = blockIdx.x, win = blockIdx.y, b = blockIdx.z;
  const int tid = threadIdx.x, lane = tid & 63, wv = tid >> 6;
  const int lr = lane & 15, lg = lane >> 4;

  __shared__ u16 q_s[48*64], k_s[48*64], v_t[64*64], p_s[48*64];
  __shared__ float smat[48*48];
  __shared__ float invq[48], invk[48];

  // zero all padded tiles (pad regions must be 0, not garbage/NaN, for MFMA)
  for (int i=tid; i<48*32; i+=256){ ((u32*)q_s)[i]=0u; ((u32*)k_s)[i]=0u; ((u32*)p_s)[i]=0u; }
  for (int i=tid; i<64*32; i+=256) ((u32*)v_t)[i]=0u;
  __syncthreads();

  const u16* base = qkv2 + (size_t)(b*NWINS + win) * (C3*SS);
  const u16* qsrc = base + (h*DD)*SS;
  const u16* ksrc = base + (CC + h*DD)*SS;
  const u16* vsrc = base + (2*CC + h*DD)*SS;
  for (int i=tid; i<DD*SS; i+=256){
    int dc = i / SS, s = i - dc*SS;
    q_s[swz(dc,s)] = qsrc[i];
    k_s[swz(dc,s)] = ksrc[i];
    v_t[swz(s,dc)] = vsrc[i];      // transposed: v_t[s][e]
  }
  __syncthreads();

  // l2-norm factors: threads 0..47 -> q rows, threads 48..95 -> k rows.
  if (tid < 96){
    int rr = (tid < 48) ? tid : (tid - 48);
    const u16* a = (tid < 48) ? q_s : k_s;
    float sum = 0.f;
    for (int s=0;s<SS;++s){ float v = bf2f(a[swz(rr,s)]); sum += v*v; }
    float inv = 1.f / fmaxf(sqrtf(sum), 1e-12f);
    if (tid < 48) invq[rr] = inv * temp[h]; else invk[rr] = inv;
  }
  __syncthreads();

  // S = q k^T : 3x3 tiles of 16x16, K=64 (49 real + zero pad)
  for (int t = wv; t < 9; t += 4){
    int ti = t/3, tj = t - ti*3;
    f32x4 c = {0.f,0.f,0.f,0.f};
    #pragma unroll
    for (int ks=0; ks<2; ++ks){
      bf16x8 a  = *(const bf16x8*)(q_s + swz(ti*16+lr, ks*32 + lg*8));
      bf16x8 bb = *(const bf16x8*)(k_s + swz(tj*16+lr, ks*32 + lg*8));
      c = __builtin_amdgcn_mfma_f32_16x16x32_bf16(a, bb, c, 0,0,0);
    }
    #pragma unroll
    for (int r=0;r<4;++r) smat[(ti*16 + lg*4 + r)*48 + tj*16 + lr] = c[r];
  }
  __syncthreads();

  // softmax rows (thread t<48 owns row t; scale by invq/invk here)
  if (tid < 48){
    const int row = tid; const float iq = invq[row];
    float m = -1e30f;
    for (int e=0;e<48;++e) m = fmaxf(m, smat[row*48+e]*iq*invk[e]);
    float sum = 0.f;
    for (int e=0;e<48;++e){
      float p = __expf(smat[row*48+e]*iq*invk[e] - m);
      smat[row*48+e] = p; sum += p;
    }
    float is = 1.f / sum;
    for (int e=0;e<48;++e) p_s[swz(row,e)] = f2bf(smat[row*48+e]*is);
  }
  __syncthreads();

  // O = P v : 3x4 tiles (d x s), K=64 (48 real e + zero pad)
  const int wy = win >> 5, wx = win & 31;
  for (int t = wv; t < 12; t += 4){
    int ti = t >> 2, tj = t & 3;
    f32x4 c = {0.f,0.f,0.f,0.f};
    #pragma unroll
    for (int ks=0; ks<2; ++ks){
      bf16x8 a  = *(const bf16x8*)(p_s + swz(ti*16+lr, ks*32 + lg*8));
      bf16x8 bb = *(const bf16x8*)(v_t + swz(tj*16+lr, ks*32 + lg*8));
      c = __builtin_amdgcn_mfma_f32_16x16x32_bf16(a, bb, c, 0,0,0);
    }
    int scol = tj*16 + lr;
    if (scol < SS){
      int pi = scol / PSZ, pj = scol - pi*PSZ;
      size_t px = (size_t)(wy*PSZ + pi)*WW2 + wx*PSZ + pj;
      #pragma unroll
      for (int r=0;r<4;++r){
        int d = ti*16 + lg*4 + r;
        aout[(size_t)(b*CC + h*DD + d)*HW + px] = f2bf(c[r]);
      }
    }
  }
}

// ---------------- launch ----------------
extern "C" void kernel_launch(void* const* d_in, const int* in_sizes, int n_in,
                              void* d_out, int out_size, void* d_ws, size_t ws_size,
                              hipStream_t stream) {
  const float* x     = (const float*)d_in[0];
  const float* qkvw  = (const float*)d_in[1];
  const float* dww   = (const float*)d_in[2];
  const float* temp  = (const float*)d_in[3];
  const float* projw = (const float*)d_in[4];
  float* out = (float*)d_out;

  // ws layout (bytes)
  const size_t SZ_QKV  = (size_t)NB*C3*HW*2;          // 231,211,008
  const size_t OFF_QKV2 = SZ_QKV;
  const size_t OFF_AO   = OFF_QKV2 + SZ_QKV;          // 462,422,016
  const size_t OFF_W1   = OFF_AO + (size_t)NB*CC*HW*2;// 539,492,352
  const size_t OFF_W2   = OFF_W1 + (size_t)C3*CC*2;   // 540,377,088
  const size_t NEEDED   = OFF_W2 + (size_t)CC*CC*2;   // 540,672,000

  if (ws_size < NEEDED){
    k_sentinel<<<(out_size + 255)/256, 256, 0, stream>>>(out, out_size);
    return;
  }
  char* ws = (char*)d_ws;
  u16* qkv  = (u16*)ws;
  u16* qkv2 = (u16*)(ws + OFF_QKV2);
  u16* ao   = (u16*)(ws + OFF_AO);
  u16* qwb  = (u16*)(ws + OFF_W1);
  u16* pwb  = (u16*)(ws + OFF_W2);

  k_cvt<<<dim3((C3*CC)/256), 256, 0, stream>>>(qkvw, projw, qwb, pwb);
  k_gemm<1,0><<<dim3(9,392,2), 256, 0, stream>>>(qwb, x, qkv);
  k_dw<<<dim3(32, C3, NB), 256, 0, stream>>>(qkv, dww, qkv2);
  k_attn<<<dim3(NHEADS, NWINS, NB), 256, 0, stream>>>(qkv2, temp, ao);
  k_gemm<0,1><<<dim3(3,392,2), 256, 0, stream>>>(pwb, ao, out);
}

// Round 4
// 851.798 us; speedup vs baseline: 2.5856x; 1.1594x over previous
//
#include <hip/hip_runtime.h>

// Channel attention (XCA windowed) for MI355X / gfx950.
// Shapes: b=2, C=384, H=W=224, heads=8, d=48, ps=7, nh=nw=32, windows=1024, s=49.
// Pipeline: [k_cvt] weights->bf16 | [k_gemm<1,0>] qkv 1x1 (MFMA) -> bf16 NCHW
//           [k_dw] depthwise 3x3, LDS-staged stripes -> bf16 [b][o][win][s] (win-records)
//           [k_attn] per-(b,win,head): l2norm+temp folded into logits, S=q k^T (MFMA),
//                    softmax rows, O=P v (MFMA) -> bf16 NCHW
//           [k_gemm<0,1>] proj 1x1 (MFMA) -> fp32 d_out

#define NB     2
#define CC     384
#define C3     1152
#define HH     224
#define WW2    224
#define HW     50176
#define NHEADS 8
#define DD     48
#define PSZ    7
#define NWINS  1024
#define SS     49
#define WS49   (NWINS*SS)   // 50176: per-channel stride in qkv2 [b][o][win][s]

typedef unsigned int  u32;
typedef unsigned short u16;
typedef __bf16 bf16x8 __attribute__((ext_vector_type(8)));
typedef float  f32x4  __attribute__((ext_vector_type(4)));

__device__ __forceinline__ u16 f2bf(float f){
  union { float f; u32 u; } v; v.f = f;
  u32 r = v.u + 0x7FFFu + ((v.u >> 16) & 1u);   // round-to-nearest-even
  return (u16)(r >> 16);
}
__device__ __forceinline__ float bf2f(u16 h){
  union { u32 u; float f; } v; v.u = ((u32)h) << 16;
  return v.f;
}

// XOR swizzle for LDS tiles with 64-ushort (128 B) rows: byte ^= ((row&7)<<4).
__device__ __forceinline__ int swz(int row, int col){
  return row*64 + ((((col << 1) ^ ((row & 7) << 4))) >> 1);
}

// ---------------- weight conversion ----------------
__global__ void k_cvt(const float* __restrict__ qw, const float* __restrict__ pw,
                      u16* __restrict__ qwb, u16* __restrict__ pwb){
  int i = blockIdx.x * 256 + threadIdx.x;
  if (i < C3*CC) qwb[i] = f2bf(qw[i]);
  if (i < CC*CC) pwb[i] = f2bf(pw[i]);
}

// ---------------- sentinel (ws too small) ----------------
__global__ void k_sentinel(float* __restrict__ out, int n){
  int i = blockIdx.x * 256 + threadIdx.x;
  if (i < n) out[i] = 12345.0f;
}

// ---------------- 1x1-conv GEMM ----------------
// C[b][m][p] = sum_k A[m][k] * B[b][k][p];  M = gridDim.x*128, K=384, N=50176.
// A: bf16 row-major [M][384]. B: fp32 or bf16 [b][384][50176]. 128x128 tile, BK=32.
template<int B_F32, int OUT_F32>
__global__ __launch_bounds__(256) void k_gemm(const u16* __restrict__ A,
    const void* __restrict__ Bsrc, void* __restrict__ Cdst){
  __shared__ u16 As[128*32];   // [m][k] row-major
  __shared__ u16 Bs[128*32];   // [n][k] (transposed at staging)
  const int m0 = blockIdx.x * 128, n0 = blockIdx.y * 128, b = blockIdx.z;
  const int M  = gridDim.x * 128;
  const int tid = threadIdx.x, lane = tid & 63, wv = tid >> 6;
  const int wm = (wv & 1) * 64, wn = (wv >> 1) * 64;
  const int lr = lane & 15, lg = lane >> 4;

  f32x4 acc[4][4];
  #pragma unroll
  for (int i=0;i<4;++i)
    #pragma unroll
    for (int j=0;j<4;++j) acc[i][j] = {0.f,0.f,0.f,0.f};

  for (int kk=0; kk<12; ++kk){
    const int k0 = kk*32;
    __syncthreads();
    // ---- stage A: 512 16-B chunks, 2 per thread (coalesced dwordx4) ----
    #pragma unroll
    for (int i=0;i<2;++i){
      int chunk = i*256 + tid;
      int row = chunk >> 2, c4 = chunk & 3;
      const uint4 v = *(const uint4*)(A + (size_t)(m0+row)*CC + k0 + c4*8);
      *(uint4*)(As + chunk*8) = v;               // chunk*8 = row*32 + c4*8
    }
    // ---- stage B transposed: thread owns k-pair (k2,k2+1), 8 n's stride 16 ----
    {
      const int k2 = (tid >> 4) * 2, nl = tid & 15;
      if (B_F32){
        const float* X = (const float*)Bsrc + (size_t)b*CC*HW + (size_t)(k0+k2)*HW + n0;
        #pragma unroll
        for (int j=0;j<8;++j){
          int n = nl + j*16;
          u32 p = (u32)f2bf(X[n]) | ((u32)f2bf(X[n+HW]) << 16);
          *(u32*)(Bs + n*32 + k2) = p;
        }
      } else {
        const u16* X = (const u16*)Bsrc + (size_t)b*CC*HW + (size_t)(k0+k2)*HW + n0;
        #pragma unroll
        for (int j=0;j<8;++j){
          int n = nl + j*16;
          u32 p = (u32)X[n] | ((u32)X[n+HW] << 16);
          *(u32*)(Bs + n*32 + k2) = p;
        }
      }
    }
    __syncthreads();
    // ---- compute: 8 ds_read_b128 + 16 MFMA ----
    bf16x8 af[4], bfr[4];
    #pragma unroll
    for (int i=0;i<4;++i) af[i]  = *(const bf16x8*)(As + (wm + i*16 + lr)*32 + lg*8);
    #pragma unroll
    for (int j=0;j<4;++j) bfr[j] = *(const bf16x8*)(Bs + (wn + j*16 + lr)*32 + lg*8);
    #pragma unroll
    for (int i=0;i<4;++i)
      #pragma unroll
      for (int j=0;j<4;++j)
        acc[i][j] = __builtin_amdgcn_mfma_f32_16x16x32_bf16(af[i], bfr[j], acc[i][j], 0, 0, 0);
  }
  // ---- epilogue: C frag col=lane&15, row=(lane>>4)*4+reg (m89) ----
  #pragma unroll
  for (int i=0;i<4;++i){
    #pragma unroll
    for (int j=0;j<4;++j){
      const int row = m0 + wm + i*16 + lg*4;
      const int col = n0 + wn + j*16 + lr;
      if (OUT_F32){
        float* Cp = (float*)Cdst + (size_t)b*M*HW;
        #pragma unroll
        for (int r=0;r<4;++r) Cp[(size_t)(row+r)*HW + col] = acc[i][j][r];
      } else {
        u16* Cp = (u16*)Cdst + (size_t)b*M*HW;
        #pragma unroll
        for (int r=0;r<4;++r) Cp[(size_t)(row+r)*HW + col] = f2bf(acc[i][j][r]);
      }
    }
  }
}

// ---------------- depthwise 3x3, SAME — LDS-staged stripes, coalesced output ----
// Block = (wy, o, b): 7 output rows x 224 cols of one channel.
// Round-3 profile: 354 us with HBM 5%, VALU 26%, 0 conflicts -> stall suspected
// in (a) 7x global_store_short 14-B scatter per thread (partial-line writes) and
// (b) runtime staging loop serializing 4 global loads. Fix: qkv2 layout
// [b][o][win][s] makes the block's whole output ONE contiguous 3136-B span ->
// stage outputs in LDS, write 196 x dwordx4; staging loop unrolled, u32-aligned.
#define DW_LD  228   // 2 (align pad) + 224 + 2 halo, u16 units; data at x+2
__global__ __launch_bounds__(256) void k_dw(const u16* __restrict__ qkv,
    const float* __restrict__ dww, u16* __restrict__ qkv2){
  const int wy = blockIdx.x, o = blockIdx.y, b = blockIdx.z;
  const int tid = threadIdx.x;
  __shared__ u16 lds[9*DW_LD];
  __shared__ u16 outbuf[32*SS];   // 1568 u16 = 3136 B

  const u16* src = qkv + (size_t)(b*C3 + o) * HW;
  const int y0 = wy*PSZ - 1;

  // stage: 9 rows x 112 u32 (224 bf16) each, coalesced, unrolled; zero OOB rows
  #pragma unroll
  for (int j=0;j<4;++j){
    int i = tid + j*256;
    if (i < 9*112){
      int r = i / 112, c2 = i - r*112;        // c2: u32 index within row
      int y = y0 + r;
      u32 v = 0u;
      if (y >= 0 && y < HH) v = *(const u32*)(src + (size_t)y*WW2 + c2*2);
      *(u32*)(lds + r*DW_LD + 2 + c2*2) = v;  // (r*228+2+2c2)*2B is 4B-aligned
    }
  }
  if (tid < 18){ int r = tid >> 1; lds[r*DW_LD + ((tid & 1) ? 226 : 1)] = 0; }  // col halos
  __syncthreads();

  if (tid < 224){
    // weights are block-uniform -> scalar loads
    float wk[9];
    #pragma unroll
    for (int i=0;i<9;++i) wk[i] = dww[o*9 + i];

    const int wx = tid / PSZ, pi = tid - wx*PSZ;
    const int xb = wx * PSZ;                  // output cols xb..xb+6
    // input x = xb+c-1 -> lds idx = x+2 = xb+c+1; rows pi..pi+2
    float row0[9], row1[9], row2[9];
    #pragma unroll
    for (int c=0;c<9;++c){
      row0[c] = bf2f(lds[(pi+0)*DW_LD + xb + c + 1]);
      row1[c] = bf2f(lds[(pi+1)*DW_LD + xb + c + 1]);
      row2[c] = bf2f(lds[(pi+2)*DW_LD + xb + c + 1]);
    }
    u16* ob = outbuf + wx*SS + pi*PSZ;
    #pragma unroll
    for (int pj=0;pj<PSZ;++pj){
      float s = 0.f;
      #pragma unroll
      for (int kx=0;kx<3;++kx){
        s += wk[0*3+kx]*row0[pj+kx];
        s += wk[1*3+kx]*row1[pj+kx];
        s += wk[2*3+kx]*row2[pj+kx];
      }
      ob[pj] = f2bf(s);
    }
  }
  __syncthreads();

  // coalesced output: 3136 B contiguous = 196 x dwordx4
  // dst base (u16): ((b*C3 + o)*NWINS + wy*32)*SS ; wy*32*49*2 = wy*3136 B (16-B aligned)
  if (tid < 196){
    u16* dst = qkv2 + ((size_t)(b*C3 + o)*NWINS + (size_t)wy*32)*SS;
    *(uint4*)(dst + tid*8) = *(const uint4*)(outbuf + tid*8);
  }
}

// ---------------- windowed channel attention ----------------
// qkv2 layout: [b][o][win][s], per-(o,win) record = 49 u16; per-channel stride WS49.
__global__ __launch_bounds__(256) void k_attn(const u16* __restrict__ qkv2,
    const float* __restrict__ temp, u16* __restrict__ aout){
  const int h = blockIdx.x, win = blockIdx.y, b = blockIdx.z;
  const int tid = threadIdx.x, lane = tid & 63, wv = tid >> 6;
  const int lr = lane & 15, lg = lane >> 4;

  __shared__ u16 q_s[48*64], k_s[48*64], v_t[64*64], p_s[48*64];
  __shared__ float smat[48*48];
  __shared__ float invq[48], invk[48];

  // zero all padded tiles (pad regions must be 0, not garbage/NaN, for MFMA)
  for (int i=tid; i<48*32; i+=256){ ((u32*)q_s)[i]=0u; ((u32*)k_s)[i]=0u; ((u32*)p_s)[i]=0u; }
  for (int i=tid; i<64*32; i+=256) ((u32*)v_t)[i]=0u;
  __syncthreads();

  const u16* qsrc = qkv2 + ((size_t)(b*C3 +          h*DD)*NWINS + win)*SS;
  const u16* ksrc = qkv2 + ((size_t)(b*C3 + CC   + h*DD)*NWINS + win)*SS;
  const u16* vsrc = qkv2 + ((size_t)(b*C3 + 2*CC + h*DD)*NWINS + win)*SS;
  for (int i=tid; i<DD*SS; i+=256){
    int dc = i / SS, s = i - dc*SS;
    size_t off = (size_t)dc*WS49 + s;
    q_s[swz(dc,s)] = qsrc[off];
    k_s[swz(dc,s)] = ksrc[off];
    v_t[swz(s,dc)] = vsrc[off];      // transposed: v_t[s][e]
  }
  __syncthreads();

  // l2-norm factors: threads 0..47 -> q rows, threads 48..95 -> k rows.
  if (tid < 96){
    int rr = (tid < 48) ? tid : (tid - 48);
    const u16* a = (tid < 48) ? q_s : k_s;
    float sum = 0.f;
    for (int s=0;s<SS;++s){ float v = bf2f(a[swz(rr,s)]); sum += v*v; }
    float inv = 1.f / fmaxf(sqrtf(sum), 1e-12f);
    if (tid < 48) invq[rr] = inv * temp[h]; else invk[rr] = inv;
  }
  __syncthreads();

  // S = q k^T : 3x3 tiles of 16x16, K=64 (49 real + zero pad)
  for (int t = wv; t < 9; t += 4){
    int ti = t/3, tj = t - ti*3;
    f32x4 c = {0.f,0.f,0.f,0.f};
    #pragma unroll
    for (int ks=0; ks<2; ++ks){
      bf16x8 a  = *(const bf16x8*)(q_s + swz(ti*16+lr, ks*32 + lg*8));
      bf16x8 bb = *(const bf16x8*)(k_s + swz(tj*16+lr, ks*32 + lg*8));
      c = __builtin_amdgcn_mfma_f32_16x16x32_bf16(a, bb, c, 0,0,0);
    }
    #pragma unroll
    for (int r=0;r<4;++r) smat[(ti*16 + lg*4 + r)*48 + tj*16 + lr] = c[r];
  }
  __syncthreads();

  // softmax rows (thread t<48 owns row t; scale by invq/invk here)
  if (tid < 48){
    const int row = tid; const float iq = invq[row];
    float m = -1e30f;
    for (int e=0;e<48;++e) m = fmaxf(m, smat[row*48+e]*iq*invk[e]);
    float sum = 0.f;
    for (int e=0;e<48;++e){
      float p = __expf(smat[row*48+e]*iq*invk[e] - m);
      smat[row*48+e] = p; sum += p;
    }
    float is = 1.f / sum;
    for (int e=0;e<48;++e) p_s[swz(row,e)] = f2bf(smat[row*48+e]*is);
  }
  __syncthreads();

  // O = P v : 3x4 tiles (d x s), K=64 (48 real e + zero pad)
  const int wy = win >> 5, wx = win & 31;
  for (int t = wv; t < 12; t += 4){
    int ti = t >> 2, tj = t & 3;
    f32x4 c = {0.f,0.f,0.f,0.f};
    #pragma unroll
    for (int ks=0; ks<2; ++ks){
      bf16x8 a  = *(const bf16x8*)(p_s + swz(ti*16+lr, ks*32 + lg*8));
      bf16x8 bb = *(const bf16x8*)(v_t + swz(tj*16+lr, ks*32 + lg*8));
      c = __builtin_amdgcn_mfma_f32_16x16x32_bf16(a, bb, c, 0,0,0);
    }
    int scol = tj*16 + lr;
    if (scol < SS){
      int pi = scol / PSZ, pj = scol - pi*PSZ;
      size_t px = (size_t)(wy*PSZ + pi)*WW2 + wx*PSZ + pj;
      #pragma unroll
      for (int r=0;r<4;++r){
        int d = ti*16 + lg*4 + r;
        aout[(size_t)(b*CC + h*DD + d)*HW + px] = f2bf(c[r]);
      }
    }
  }
}

// ---------------- launch ----------------
extern "C" void kernel_launch(void* const* d_in, const int* in_sizes, int n_in,
                              void* d_out, int out_size, void* d_ws, size_t ws_size,
                              hipStream_t stream) {
  const float* x     = (const float*)d_in[0];
  const float* qkvw  = (const float*)d_in[1];
  const float* dww   = (const float*)d_in[2];
  const float* temp  = (const float*)d_in[3];
  const float* projw = (const float*)d_in[4];
  float* out = (float*)d_out;

  // ws layout (bytes)
  const size_t SZ_QKV  = (size_t)NB*C3*HW*2;          // 231,211,008
  const size_t OFF_QKV2 = SZ_QKV;
  const size_t OFF_AO   = OFF_QKV2 + SZ_QKV;          // 462,422,016
  const size_t OFF_W1   = OFF_AO + (size_t)NB*CC*HW*2;// 539,492,352
  const size_t OFF_W2   = OFF_W1 + (size_t)C3*CC*2;   // 540,377,088
  const size_t NEEDED   = OFF_W2 + (size_t)CC*CC*2;   // 540,672,000

  if (ws_size < NEEDED){
    k_sentinel<<<(out_size + 255)/256, 256, 0, stream>>>(out, out_size);
    return;
  }
  char* ws = (char*)d_ws;
  u16* qkv  = (u16*)ws;
  u16* qkv2 = (u16*)(ws + OFF_QKV2);
  u16* ao   = (u16*)(ws + OFF_AO);
  u16* qwb  = (u16*)(ws + OFF_W1);
  u16* pwb  = (u16*)(ws + OFF_W2);

  k_cvt<<<dim3((C3*CC)/256), 256, 0, stream>>>(qkvw, projw, qwb, pwb);
  k_gemm<1,0><<<dim3(9,392,2), 256, 0, stream>>>(qwb, x, qkv);
  k_dw<<<dim3(32, C3, NB), 256, 0, stream>>>(qkv, dww, qkv2);
  k_attn<<<dim3(NHEADS, NWINS, NB), 256, 0, stream>>>(qkv2, temp, ao);
  k_gemm<0,1><<<dim3(3,392,2), 256, 0, stream>>>(pwb, ao, out);
}

// Round 5
// 633.590 us; speedup vs baseline: 3.4761x; 1.3444x over previous
//
#include <hip/hip_runtime.h>

// Channel attention (XCA windowed) for MI355X / gfx950.
// Shapes: b=2, C=384, H=W=224, heads=8, d=48, ps=7, nh=nw=32, windows=1024, s=49.
// Pipeline: [k_cvt] weights->bf16 | [k_gemm<1,0>] qkv 1x1 (MFMA) -> bf16 NCHW
//           [k_dw] depthwise 3x3 (2 ch/block) -> bf16 [b][o][win][50] (padded records)
//           [k_attn] per-(b,win,head): in-register softmax, S=q k^T (MFMA), O=P v (MFMA)
//           [k_gemm<0,1>] proj 1x1 (MFMA) -> fp32 d_out
// ws aliasing: ao (attn out, 77 MB) overlays qkv (dead after k_dw).

#define NB     2
#define CC     384
#define C3     1152
#define HH     224
#define WW2    224
#define HW     50176
#define NHEADS 8
#define DD     48
#define PSZ    7
#define NWINS  1024
#define SS     49
#define SSP    50                 // padded record length (4-B alignment; slot 49 = 0)
#define WS50   (NWINS*SSP)        // 51200: per-channel stride in qkv2

typedef unsigned int  u32;
typedef unsigned short u16;
typedef __bf16 bf16x8 __attribute__((ext_vector_type(8)));
typedef float  f32x4  __attribute__((ext_vector_type(4)));

__device__ __forceinline__ u16 f2bf(float f){
  union { float f; u32 u; } v; v.f = f;
  u32 r = v.u + 0x7FFFu + ((v.u >> 16) & 1u);   // round-to-nearest-even
  return (u16)(r >> 16);
}
__device__ __forceinline__ float bf2f(u16 h){
  union { u32 u; float f; } v; v.u = ((u32)h) << 16;
  return v.f;
}

// XOR swizzle for LDS tiles with 64-ushort (128 B) rows: u16idx = r*64 + (c ^ ((r&7)<<3)).
// 16-B-block-preserving involution; adjacent even/odd cols stay adjacent (u32-writable).
__device__ __forceinline__ int swz(int row, int col){
  return row*64 + (col ^ ((row & 7) << 3));
}

// ---------------- weight conversion ----------------
__global__ void k_cvt(const float* __restrict__ qw, const float* __restrict__ pw,
                      u16* __restrict__ qwb, u16* __restrict__ pwb){
  int i = blockIdx.x * 256 + threadIdx.x;
  if (i < C3*CC) qwb[i] = f2bf(qw[i]);
  if (i < CC*CC) pwb[i] = f2bf(pw[i]);
}

// ---------------- sentinel (ws too small) ----------------
__global__ void k_sentinel(float* __restrict__ out, int n){
  int i = blockIdx.x * 256 + threadIdx.x;
  if (i < n) out[i] = 12345.0f;
}

// ---------------- 1x1-conv GEMM ----------------
// C[b][m][p] = sum_k A[m][k] * B[b][k][p];  M = gridDim.x*128, K=384, N=50176.
template<int B_F32, int OUT_F32>
__global__ __launch_bounds__(256) void k_gemm(const u16* __restrict__ A,
    const void* __restrict__ Bsrc, void* __restrict__ Cdst){
  __shared__ __align__(16) u16 As[128*32];   // [m][k] row-major
  __shared__ __align__(16) u16 Bs[128*32];   // [n][k] (transposed at staging)
  const int m0 = blockIdx.x * 128, n0 = blockIdx.y * 128, b = blockIdx.z;
  const int M  = gridDim.x * 128;
  const int tid = threadIdx.x, lane = tid & 63, wv = tid >> 6;
  const int wm = (wv & 1) * 64, wn = (wv >> 1) * 64;
  const int lr = lane & 15, lg = lane >> 4;

  f32x4 acc[4][4];
  #pragma unroll
  for (int i=0;i<4;++i)
    #pragma unroll
    for (int j=0;j<4;++j) acc[i][j] = {0.f,0.f,0.f,0.f};

  for (int kk=0; kk<12; ++kk){
    const int k0 = kk*32;
    __syncthreads();
    // ---- stage A: 512 16-B chunks, 2 per thread ----
    #pragma unroll
    for (int i=0;i<2;++i){
      int chunk = i*256 + tid;
      int row = chunk >> 2, c4 = chunk & 3;
      const uint4 v = *(const uint4*)(A + (size_t)(m0+row)*CC + k0 + c4*8);
      *(uint4*)(As + chunk*8) = v;
    }
    // ---- stage B transposed: thread owns k-pair, 8 n's stride 16 ----
    {
      const int k2 = (tid >> 4) * 2, nl = tid & 15;
      if (B_F32){
        const float* X = (const float*)Bsrc + (size_t)b*CC*HW + (size_t)(k0+k2)*HW + n0;
        #pragma unroll
        for (int j=0;j<8;++j){
          int n = nl + j*16;
          u32 p = (u32)f2bf(X[n]) | ((u32)f2bf(X[n+HW]) << 16);
          *(u32*)(Bs + n*32 + k2) = p;
        }
      } else {
        const u16* X = (const u16*)Bsrc + (size_t)b*CC*HW + (size_t)(k0+k2)*HW + n0;
        #pragma unroll
        for (int j=0;j<8;++j){
          int n = nl + j*16;
          u32 p = (u32)X[n] | ((u32)X[n+HW] << 16);
          *(u32*)(Bs + n*32 + k2) = p;
        }
      }
    }
    __syncthreads();
    // ---- compute: 8 ds_read_b128 + 16 MFMA ----
    bf16x8 af[4], bfr[4];
    #pragma unroll
    for (int i=0;i<4;++i) af[i]  = *(const bf16x8*)(As + (wm + i*16 + lr)*32 + lg*8);
    #pragma unroll
    for (int j=0;j<4;++j) bfr[j] = *(const bf16x8*)(Bs + (wn + j*16 + lr)*32 + lg*8);
    #pragma unroll
    for (int i=0;i<4;++i)
      #pragma unroll
      for (int j=0;j<4;++j)
        acc[i][j] = __builtin_amdgcn_mfma_f32_16x16x32_bf16(af[i], bfr[j], acc[i][j], 0, 0, 0);
  }
  // ---- epilogue: C frag col=lane&15, row=(lane>>4)*4+reg (m89) ----
  #pragma unroll
  for (int i=0;i<4;++i){
    #pragma unroll
    for (int j=0;j<4;++j){
      const int row = m0 + wm + i*16 + lg*4;
      const int col = n0 + wn + j*16 + lr;
      if (OUT_F32){
        float* Cp = (float*)Cdst + (size_t)b*M*HW;
        #pragma unroll
        for (int r=0;r<4;++r) Cp[(size_t)(row+r)*HW + col] = acc[i][j][r];
      } else {
        u16* Cp = (u16*)Cdst + (size_t)b*M*HW;
        #pragma unroll
        for (int r=0;r<4;++r) Cp[(size_t)(row+r)*HW + col] = f2bf(acc[i][j][r]);
      }
    }
  }
}

// ---------------- depthwise 3x3, SAME — 2 channels/block ----------------
// Block = (wy, o-pair, b). Round-4: k_dw latency-bound (HBM 5%, VALU 26%) with
// only 4 staged loads/thread; 2 ch/block doubles loads in flight and halves
// block/barrier count. Output records padded to 50 u16 (slot 49 = 0) so k_attn
// can stage with aligned u32 loads.
#define DW_LD  228   // 2 (align pad) + 224 + 2 halo, u16 units; data at x+2
__global__ __launch_bounds__(256) void k_dw(const u16* __restrict__ qkv,
    const float* __restrict__ dww, u16* __restrict__ qkv2){
  const int wy = blockIdx.x, o0 = blockIdx.y*2, b = blockIdx.z;
  const int tid = threadIdx.x;
  __shared__ __align__(16) u16 lin[2][9*DW_LD];
  __shared__ __align__(16) u16 outb[2][32*SSP];

  const int y0 = wy*PSZ - 1;
  // stage both channels: 9 rows x 112 u32 each, coalesced, unrolled
  #pragma unroll
  for (int ch=0; ch<2; ++ch){
    const u16* src = qkv + (size_t)(b*C3 + o0 + ch) * HW;
    #pragma unroll
    for (int j=0;j<4;++j){
      int i = tid + j*256;
      if (i < 9*112){
        int r = i / 112, c2 = i - r*112;
        int y = y0 + r;
        u32 v = 0u;
        if (y >= 0 && y < HH) v = *(const u32*)(src + (size_t)y*WW2 + c2*2);
        *(u32*)(lin[ch] + r*DW_LD + 2 + c2*2) = v;
      }
    }
  }
  if (tid < 36){ int ch = tid/18, t = tid%18; int r = t>>1;
                 lin[ch][r*DW_LD + ((t&1) ? 226 : 1)] = 0; }      // col halos
  if (tid >= 192 && tid < 256){ int t = tid-192; outb[t>>5][(t&31)*SSP + 49] = 0; } // pad slot
  __syncthreads();

  if (tid < 224){
    const int wx = tid / PSZ, pi = tid - wx*PSZ;
    const int xb = wx * PSZ;
    #pragma unroll
    for (int ch=0; ch<2; ++ch){
      float wk[9];
      #pragma unroll
      for (int i=0;i<9;++i) wk[i] = dww[(o0+ch)*9 + i];
      float row0[9], row1[9], row2[9];
      #pragma unroll
      for (int c=0;c<9;++c){
        row0[c] = bf2f(lin[ch][(pi+0)*DW_LD + xb + c + 1]);
        row1[c] = bf2f(lin[ch][(pi+1)*DW_LD + xb + c + 1]);
        row2[c] = bf2f(lin[ch][(pi+2)*DW_LD + xb + c + 1]);
      }
      u16* ob = outb[ch] + wx*SSP + pi*PSZ;
      #pragma unroll
      for (int pj=0;pj<PSZ;++pj){
        float s = 0.f;
        #pragma unroll
        for (int kx=0;kx<3;++kx){
          s += wk[0*3+kx]*row0[pj+kx];
          s += wk[1*3+kx]*row1[pj+kx];
          s += wk[2*3+kx]*row2[pj+kx];
        }
        ob[pj] = f2bf(s);
      }
    }
  }
  __syncthreads();

  // coalesced output: 2 channels x 3200 B contiguous = 400 x dwordx4
  #pragma unroll
  for (int j=0;j<2;++j){
    int i = tid + j*256;
    if (i < 400){
      int ch = i / 200, idx = i - ch*200;
      u16* dst = qkv2 + ((size_t)(b*C3 + o0 + ch)*NWINS + (size_t)wy*32)*SSP;
      *(uint4*)(dst + idx*8) = *(const uint4*)(outb[ch] + idx*8);
    }
  }
}

// ---------------- windowed channel attention ----------------
// Block = (head, win, b), 4 waves. Round-4 profile: 360 us, BANK_CONFLICT 4.1e7,
// MfmaUtil 1.2% -> serial 48-thread softmax over fp32 smat (stride-48 = 24-way
// conflicts) dominated. Now: waves 0..2 each compute S row-tile ti=wv (3 tj tiles
// in registers) and do softmax fully in-register (shfl_xor butterfly over the
// 16-lane col groups); smat eliminated; staging via aligned u32 (SSP=50 records).
__global__ __launch_bounds__(256) void k_attn(const u16* __restrict__ qkv2,
    const float* __restrict__ temp, u16* __restrict__ aout){
  const int h = blockIdx.x, win = blockIdx.y, b = blockIdx.z;
  const int tid = threadIdx.x, lane = tid & 63, wv = tid >> 6;
  const int lr = lane & 15, lg = lane >> 4;

  __shared__ __align__(16) u16 q_s[48*64], k_s[48*64], v_t[64*64], p_s[48*64];
  __shared__ float invq[48], invk[48];

  // zero all padded tiles (pads must be 0, not garbage/NaN: 0*NaN = NaN in MFMA)
  for (int i=tid; i<48*32; i+=256){ ((u32*)q_s)[i]=0u; ((u32*)k_s)[i]=0u; ((u32*)p_s)[i]=0u; }
  for (int i=tid; i<64*32; i+=256) ((u32*)v_t)[i]=0u;
  __syncthreads();

  // stage q,k,v: 48 records x 25 u32 chunks each (slot 49 is 0 from k_dw)
  const u16* qsrc = qkv2 + ((size_t)(b*C3 +        h*DD)*NWINS + win)*SSP;
  const u16* ksrc = qkv2 + ((size_t)(b*C3 + CC   + h*DD)*NWINS + win)*SSP;
  const u16* vsrc = qkv2 + ((size_t)(b*C3 + 2*CC + h*DD)*NWINS + win)*SSP;
  for (int i=tid; i<48*25; i+=256){
    int dc = i / 25, c = i - dc*25;
    size_t off = (size_t)dc*WS50 + 2*c;
    u32 vq = *(const u32*)(qsrc + off);
    u32 vk = *(const u32*)(ksrc + off);
    u32 vv = *(const u32*)(vsrc + off);
    int sw = swz(dc, 2*c);
    *(u32*)(q_s + sw) = vq;
    *(u32*)(k_s + sw) = vk;
    v_t[swz(2*c,   dc)] = (u16)(vv & 0xffffu);   // transposed: v_t[s][e]
    v_t[swz(2*c+1, dc)] = (u16)(vv >> 16);
  }
  __syncthreads();

  // l2-norm factors: 192 threads, 2 per row (halves combined via shfl_xor(1))
  if (tid < 192){
    const int row96 = tid >> 1, half = tid & 1;
    const int rr = (row96 < 48) ? row96 : row96 - 48;
    const u16* a = (row96 < 48) ? q_s : k_s;
    const int s0 = half ? 25 : 0, s1 = half ? 49 : 25;
    float sum = 0.f;
    for (int s=s0; s<s1; ++s){ float v = bf2f(a[swz(rr,s)]); sum += v*v; }
    sum += __shfl_xor(sum, 1);
    if (!half){
      float inv = 1.f / fmaxf(sqrtf(sum), 1e-12f);
      if (row96 < 48) invq[rr] = inv * temp[h]; else invk[rr] = inv;
    }
  }
  __syncthreads();

  // S = q k^T, softmax in-register. Wave wv<3 owns row-tile ti=wv (16 rows).
  if (wv < 3){
    const int ti = wv;
    f32x4 c3[3];
    #pragma unroll
    for (int tj=0;tj<3;++tj) c3[tj] = {0.f,0.f,0.f,0.f};
    #pragma unroll
    for (int tj=0;tj<3;++tj){
      #pragma unroll
      for (int ks=0; ks<2; ++ks){
        bf16x8 a  = *(const bf16x8*)(q_s + swz(ti*16+lr, ks*32 + lg*8));
        bf16x8 bb = *(const bf16x8*)(k_s + swz(tj*16+lr, ks*32 + lg*8));
        c3[tj] = __builtin_amdgcn_mfma_f32_16x16x32_bf16(a, bb, c3[tj], 0,0,0);
      }
    }
    // scales: C-frag row = ti*16+lg*4+r, col = tj*16+lr
    const float ik0 = invk[lr], ik1 = invk[16+lr], ik2 = invk[32+lr];
    #pragma unroll
    for (int r=0;r<4;++r){
      const int row = ti*16 + lg*4 + r;
      const float iq = invq[row];
      float l0 = c3[0][r]*iq*ik0, l1 = c3[1][r]*iq*ik1, l2 = c3[2][r]*iq*ik2;
      float m = fmaxf(fmaxf(l0,l1),l2);
      m = fmaxf(m, __shfl_xor(m,1)); m = fmaxf(m, __shfl_xor(m,2));
      m = fmaxf(m, __shfl_xor(m,4)); m = fmaxf(m, __shfl_xor(m,8));
      float e0 = __expf(l0-m), e1 = __expf(l1-m), e2 = __expf(l2-m);
      float s = e0+e1+e2;
      s += __shfl_xor(s,1); s += __shfl_xor(s,2);
      s += __shfl_xor(s,4); s += __shfl_xor(s,8);
      const float is = 1.f / s;
      p_s[swz(row, lr)]    = f2bf(e0*is);
      p_s[swz(row, 16+lr)] = f2bf(e1*is);
      p_s[swz(row, 32+lr)] = f2bf(e2*is);
    }
  }
  __syncthreads();

  // O = P v : 12 tiles (3 d-tiles x 4 s-tiles) across 4 waves, K=64
  const int wy = win >> 5, wx = win & 31;
  for (int t = wv; t < 12; t += 4){
    int ti = t >> 2, tj = t & 3;
    f32x4 c = {0.f,0.f,0.f,0.f};
    #pragma unroll
    for (int ks=0; ks<2; ++ks){
      bf16x8 a  = *(const bf16x8*)(p_s + swz(ti*16+lr, ks*32 + lg*8));
      bf16x8 bb = *(const bf16x8*)(v_t + swz(tj*16+lr, ks*32 + lg*8));
      c = __builtin_amdgcn_mfma_f32_16x16x32_bf16(a, bb, c, 0,0,0);
    }
    int scol = tj*16 + lr;
    if (scol < SS){
      int pi = scol / PSZ, pj = scol - pi*PSZ;
      size_t px = (size_t)(wy*PSZ + pi)*WW2 + wx*PSZ + pj;
      #pragma unroll
      for (int r=0;r<4;++r){
        int d = ti*16 + lg*4 + r;
        aout[(size_t)(b*CC + h*DD + d)*HW + px] = f2bf(c[r]);
      }
    }
  }
}

// ---------------- launch ----------------
extern "C" void kernel_launch(void* const* d_in, const int* in_sizes, int n_in,
                              void* d_out, int out_size, void* d_ws, size_t ws_size,
                              hipStream_t stream) {
  const float* x     = (const float*)d_in[0];
  const float* qkvw  = (const float*)d_in[1];
  const float* dww   = (const float*)d_in[2];
  const float* temp  = (const float*)d_in[3];
  const float* projw = (const float*)d_in[4];
  float* out = (float*)d_out;

  // ws layout (bytes); ao aliases qkv (dead after k_dw)
  const size_t SZ_QKV   = (size_t)NB*C3*HW*2;            // 231,211,008
  const size_t SZ_QKV2  = (size_t)NB*C3*NWINS*SSP*2;     // 235,929,600
  const size_t OFF_QKV2 = SZ_QKV;
  const size_t OFF_W1   = OFF_QKV2 + SZ_QKV2;            // 467,140,608
  const size_t OFF_W2   = OFF_W1 + (size_t)C3*CC*2;
  const size_t NEEDED   = OFF_W2 + (size_t)CC*CC*2;      // 468,320,256

  if (ws_size < NEEDED){
    k_sentinel<<<(out_size + 255)/256, 256, 0, stream>>>(out, out_size);
    return;
  }
  char* ws = (char*)d_ws;
  u16* qkv  = (u16*)ws;
  u16* qkv2 = (u16*)(ws + OFF_QKV2);
  u16* ao   = (u16*)ws;                 // aliases qkv
  u16* qwb  = (u16*)(ws + OFF_W1);
  u16* pwb  = (u16*)(ws + OFF_W2);

  k_cvt<<<dim3((C3*CC)/256), 256, 0, stream>>>(qkvw, projw, qwb, pwb);
  k_gemm<1,0><<<dim3(9,392,2), 256, 0, stream>>>(qwb, x, qkv);
  k_dw<<<dim3(32, C3/2, NB), 256, 0, stream>>>(qkv, dww, qkv2);
  k_attn<<<dim3(NHEADS, NWINS, NB), 256, 0, stream>>>(qkv2, temp, ao);
  k_gemm<0,1><<<dim3(3,392,2), 256, 0, stream>>>(pwb, ao, out);
}

// Round 6
// 577.390 us; speedup vs baseline: 3.8145x; 1.0973x over previous
//
#include <hip/hip_runtime.h>

// Channel attention (XCA windowed) for MI355X / gfx950.
// Shapes: b=2, C=384, H=W=224, heads=8, d=48, ps=7, nh=nw=32, windows=1024, s=49.
// Pipeline: [k_cvt] weights->bf16       [k_trx] x fp32 NCHW -> bf16 NHWC xt[b][p][c]
//           [k_gemm<0>] qkv 1x1 (MFMA, global_load_lds staging) -> bf16 NCHW
//           [k_dw] depthwise 3x3 (2 ch/block) -> bf16 [b][o][win][50]
//           [k_attn] in-register softmax attention -> bf16 NHWC ao[b][p][c]
//           [k_gemm<1>] proj 1x1 -> fp32 NCHW d_out
// ws aliasing: xt overlays qkv2 region (dead before k_dw); ao overlays qkv.

#define NB     2
#define CC     384
#define C3     1152
#define HH     224
#define WW2    224
#define HW     50176
#define NHEADS 8
#define DD     48
#define PSZ    7
#define NWINS  1024
#define SS     49
#define SSP    50                 // padded record length (4-B alignment; slot 49 = 0)
#define WS50   (NWINS*SSP)        // 51200: per-channel stride in qkv2

typedef unsigned int  u32;
typedef unsigned short u16;
typedef __bf16 bf16x8 __attribute__((ext_vector_type(8)));
typedef float  f32x4  __attribute__((ext_vector_type(4)));

__device__ __forceinline__ u16 f2bf(float f){
  union { float f; u32 u; } v; v.f = f;
  u32 r = v.u + 0x7FFFu + ((v.u >> 16) & 1u);   // round-to-nearest-even
  return (u16)(r >> 16);
}
__device__ __forceinline__ float bf2f(u16 h){
  union { u32 u; float f; } v; v.u = ((u32)h) << 16;
  return v.f;
}

// async global->LDS, 16 B per lane (CK address-space idiom; LDS dest is
// wave-uniform base + lane*16, so per-call lds ptrs must be lane-linear).
typedef __attribute__((address_space(3))) u32 as3_u32;
typedef __attribute__((address_space(1))) const u32 as1_u32;
__device__ __forceinline__ void gld16(const void* g, void* l){
  __builtin_amdgcn_global_load_lds((as1_u32*)(unsigned long long)(g),
                                   (as3_u32*)(u32)(unsigned long long)(l),
                                   16, 0, 0);
}

// XOR swizzle for LDS tiles with 64-ushort (128 B) rows (attn tiles).
__device__ __forceinline__ int swz(int row, int col){
  return row*64 + (col ^ ((row & 7) << 3));
}

// ---------------- weight conversion ----------------
__global__ void k_cvt(const float* __restrict__ qw, const float* __restrict__ pw,
                      u16* __restrict__ qwb, u16* __restrict__ pwb){
  int i = blockIdx.x * 256 + threadIdx.x;
  if (i < C3*CC) qwb[i] = f2bf(qw[i]);
  if (i < CC*CC) pwb[i] = f2bf(pw[i]);
}

// ---------------- sentinel (ws too small) ----------------
__global__ void k_sentinel(float* __restrict__ out, int n){
  int i = blockIdx.x * 256 + threadIdx.x;
  if (i < n) out[i] = 12345.0f;
}

// ---------------- x transpose+convert: NCHW fp32 -> NHWC bf16 ----------------
// Block = (p-tile of 64, b). LDS [p][c] with CPAD=386 (2-way max on both phases).
#define CPAD 386
__global__ __launch_bounds__(256) void k_trx(const float* __restrict__ x,
                                             u16* __restrict__ xt){
  const int pt = blockIdx.x, b = blockIdx.y, tid = threadIdx.x;
  __shared__ u16 t[64*CPAD];
  const float* xb = x + (size_t)b*CC*HW + pt*64;
  // read: 6144 float4 = [c:384][p4:16], coalesced 256 B per 16 lanes
  #pragma unroll
  for (int it=0; it<24; ++it){
    int i = tid + it*256;
    int c = i >> 4, p4 = (i & 15)*4;
    float4 v = *(const float4*)(xb + (size_t)c*HW + p4);
    t[(p4+0)*CPAD + c] = f2bf(v.x);
    t[(p4+1)*CPAD + c] = f2bf(v.y);
    t[(p4+2)*CPAD + c] = f2bf(v.z);
    t[(p4+3)*CPAD + c] = f2bf(v.w);
  }
  __syncthreads();
  // write: 64 p-rows x 192 u32, fully contiguous 49 KB span
  u32* dst = (u32*)(xt + ((size_t)b*HW + (size_t)pt*64)*CC);
  #pragma unroll
  for (int it=0; it<48; ++it){
    int j = tid + it*256;
    int p = j / 192, c2 = j - p*192;
    dst[j] = *(const u32*)(t + p*CPAD + c2*2);
  }
}

// ---------------- 1x1-conv GEMM (symmetric bf16 staging) ----------------
// C[b][m][p] = sum_k A[m][k] * B[b][p][k];  A row-major [M][384] bf16,
// B = NHWC bf16 [b][HW][384]. 128x128 tile, BK=32, global_load_lds staging.
template<int OUT_F32>
__global__ __launch_bounds__(256) void k_gemm(const u16* __restrict__ A,
    const u16* __restrict__ B, void* __restrict__ Cdst){
  __shared__ __align__(16) u16 As[128*32];   // [m][k]
  __shared__ __align__(16) u16 Bs[128*32];   // [n][k]
  const int m0 = blockIdx.x * 128, n0 = blockIdx.y * 128, b = blockIdx.z;
  const int M  = gridDim.x * 128;
  const int tid = threadIdx.x, lane = tid & 63, wv = tid >> 6;
  const int wm = (wv & 1) * 64, wn = (wv >> 1) * 64;
  const int lr = lane & 15, lg = lane >> 4;
  const u16* Bb = B + (size_t)b*HW*CC;

  f32x4 acc[4][4];
  #pragma unroll
  for (int i=0;i<4;++i)
    #pragma unroll
    for (int j=0;j<4;++j) acc[i][j] = {0.f,0.f,0.f,0.f};

  for (int kk=0; kk<12; ++kk){
    const int k0 = kk*32;
    __syncthreads();
    // stage A and B: 512 16-B chunks each, 2/thread, direct-to-LDS
    #pragma unroll
    for (int i=0;i<2;++i){
      int chunk = i*256 + tid;
      int row = chunk >> 2, c4 = chunk & 3;
      gld16(A  + (size_t)(m0+row)*CC + k0 + c4*8, As + chunk*8);
      gld16(Bb + (size_t)(n0+row)*CC + k0 + c4*8, Bs + chunk*8);
    }
    __syncthreads();   // compiler drains vmcnt before barrier
    // compute: 8 ds_read_b128 + 16 MFMA
    bf16x8 af[4], bfr[4];
    #pragma unroll
    for (int i=0;i<4;++i) af[i]  = *(const bf16x8*)(As + (wm + i*16 + lr)*32 + lg*8);
    #pragma unroll
    for (int j=0;j<4;++j) bfr[j] = *(const bf16x8*)(Bs + (wn + j*16 + lr)*32 + lg*8);
    #pragma unroll
    for (int i=0;i<4;++i)
      #pragma unroll
      for (int j=0;j<4;++j)
        acc[i][j] = __builtin_amdgcn_mfma_f32_16x16x32_bf16(af[i], bfr[j], acc[i][j], 0, 0, 0);
  }
  // epilogue: C frag col=lane&15 (-> B row = pixel), row=(lane>>4)*4+reg (-> A row)
  #pragma unroll
  for (int i=0;i<4;++i){
    #pragma unroll
    for (int j=0;j<4;++j){
      const int row = m0 + wm + i*16 + lg*4;
      const int col = n0 + wn + j*16 + lr;
      if (OUT_F32){
        float* Cp = (float*)Cdst + (size_t)b*M*HW;
        #pragma unroll
        for (int r=0;r<4;++r) Cp[(size_t)(row+r)*HW + col] = acc[i][j][r];
      } else {
        u16* Cp = (u16*)Cdst + (size_t)b*M*HW;
        #pragma unroll
        for (int r=0;r<4;++r) Cp[(size_t)(row+r)*HW + col] = f2bf(acc[i][j][r]);
      }
    }
  }
}

// ---------------- depthwise 3x3, SAME — 2 channels/block ----------------
#define DW_LD  228   // 2 (align pad) + 224 + 2 halo, u16 units; data at x+2
__global__ __launch_bounds__(256) void k_dw(const u16* __restrict__ qkv,
    const float* __restrict__ dww, u16* __restrict__ qkv2){
  const int wy = blockIdx.x, o0 = blockIdx.y*2, b = blockIdx.z;
  const int tid = threadIdx.x;
  __shared__ __align__(16) u16 lin[2][9*DW_LD];
  __shared__ __align__(16) u16 outb[2][32*SSP];

  const int y0 = wy*PSZ - 1;
  #pragma unroll
  for (int ch=0; ch<2; ++ch){
    const u16* src = qkv + (size_t)(b*C3 + o0 + ch) * HW;
    #pragma unroll
    for (int j=0;j<4;++j){
      int i = tid + j*256;
      if (i < 9*112){
        int r = i / 112, c2 = i - r*112;
        int y = y0 + r;
        u32 v = 0u;
        if (y >= 0 && y < HH) v = *(const u32*)(src + (size_t)y*WW2 + c2*2);
        *(u32*)(lin[ch] + r*DW_LD + 2 + c2*2) = v;
      }
    }
  }
  if (tid < 36){ int ch = tid/18, t = tid%18; int r = t>>1;
                 lin[ch][r*DW_LD + ((t&1) ? 226 : 1)] = 0; }      // col halos
  if (tid >= 192 && tid < 256){ int t = tid-192; outb[t>>5][(t&31)*SSP + 49] = 0; }
  __syncthreads();

  if (tid < 224){
    const int wx = tid / PSZ, pi = tid - wx*PSZ;
    const int xb = wx * PSZ;
    #pragma unroll
    for (int ch=0; ch<2; ++ch){
      float wk[9];
      #pragma unroll
      for (int i=0;i<9;++i) wk[i] = dww[(o0+ch)*9 + i];
      float row0[9], row1[9], row2[9];
      #pragma unroll
      for (int c=0;c<9;++c){
        row0[c] = bf2f(lin[ch][(pi+0)*DW_LD + xb + c + 1]);
        row1[c] = bf2f(lin[ch][(pi+1)*DW_LD + xb + c + 1]);
        row2[c] = bf2f(lin[ch][(pi+2)*DW_LD + xb + c + 1]);
      }
      u16* ob = outb[ch] + wx*SSP + pi*PSZ;
      #pragma unroll
      for (int pj=0;pj<PSZ;++pj){
        float s = 0.f;
        #pragma unroll
        for (int kx=0;kx<3;++kx){
          s += wk[0*3+kx]*row0[pj+kx];
          s += wk[1*3+kx]*row1[pj+kx];
          s += wk[2*3+kx]*row2[pj+kx];
        }
        ob[pj] = f2bf(s);
      }
    }
  }
  __syncthreads();

  #pragma unroll
  for (int j=0;j<2;++j){
    int i = tid + j*256;
    if (i < 400){
      int ch = i / 200, idx = i - ch*200;
      u16* dst = qkv2 + ((size_t)(b*C3 + o0 + ch)*NWINS + (size_t)wy*32)*SSP;
      *(uint4*)(dst + idx*8) = *(const uint4*)(outb[ch] + idx*8);
    }
  }
}

// ---------------- windowed channel attention ----------------
// Block = (head, win, b), 4 waves; in-register softmax (round-5).
// Output now NHWC ao[b][p][c]: lane's 4 acc rows = 4 consecutive channels ->
// one 8-B store (was 4x 2-B stores at 100-KB stride).
__global__ __launch_bounds__(256) void k_attn(const u16* __restrict__ qkv2,
    const float* __restrict__ temp, u16* __restrict__ aout){
  const int h = blockIdx.x, win = blockIdx.y, b = blockIdx.z;
  const int tid = threadIdx.x, lane = tid & 63, wv = tid >> 6;
  const int lr = lane & 15, lg = lane >> 4;

  __shared__ __align__(16) u16 q_s[48*64], k_s[48*64], v_t[64*64], p_s[48*64];
  __shared__ float invq[48], invk[48];

  for (int i=tid; i<48*32; i+=256){ ((u32*)q_s)[i]=0u; ((u32*)k_s)[i]=0u; ((u32*)p_s)[i]=0u; }
  for (int i=tid; i<64*32; i+=256) ((u32*)v_t)[i]=0u;
  __syncthreads();

  const u16* qsrc = qkv2 + ((size_t)(b*C3 +        h*DD)*NWINS + win)*SSP;
  const u16* ksrc = qkv2 + ((size_t)(b*C3 + CC   + h*DD)*NWINS + win)*SSP;
  const u16* vsrc = qkv2 + ((size_t)(b*C3 + 2*CC + h*DD)*NWINS + win)*SSP;
  for (int i=tid; i<48*25; i+=256){
    int dc = i / 25, c = i - dc*25;
    size_t off = (size_t)dc*WS50 + 2*c;
    u32 vq = *(const u32*)(qsrc + off);
    u32 vk = *(const u32*)(ksrc + off);
    u32 vv = *(const u32*)(vsrc + off);
    int sw = swz(dc, 2*c);
    *(u32*)(q_s + sw) = vq;
    *(u32*)(k_s + sw) = vk;
    v_t[swz(2*c,   dc)] = (u16)(vv & 0xffffu);
    v_t[swz(2*c+1, dc)] = (u16)(vv >> 16);
  }
  __syncthreads();

  if (tid < 192){
    const int row96 = tid >> 1, half = tid & 1;
    const int rr = (row96 < 48) ? row96 : row96 - 48;
    const u16* a = (row96 < 48) ? q_s : k_s;
    const int s0 = half ? 25 : 0, s1 = half ? 49 : 25;
    float sum = 0.f;
    for (int s=s0; s<s1; ++s){ float v = bf2f(a[swz(rr,s)]); sum += v*v; }
    sum += __shfl_xor(sum, 1);
    if (!half){
      float inv = 1.f / fmaxf(sqrtf(sum), 1e-12f);
      if (row96 < 48) invq[rr] = inv * temp[h]; else invk[rr] = inv;
    }
  }
  __syncthreads();

  if (wv < 3){
    const int ti = wv;
    f32x4 c3[3];
    #pragma unroll
    for (int tj=0;tj<3;++tj) c3[tj] = {0.f,0.f,0.f,0.f};
    #pragma unroll
    for (int tj=0;tj<3;++tj){
      #pragma unroll
      for (int ks=0; ks<2; ++ks){
        bf16x8 a  = *(const bf16x8*)(q_s + swz(ti*16+lr, ks*32 + lg*8));
        bf16x8 bb = *(const bf16x8*)(k_s + swz(tj*16+lr, ks*32 + lg*8));
        c3[tj] = __builtin_amdgcn_mfma_f32_16x16x32_bf16(a, bb, c3[tj], 0,0,0);
      }
    }
    const float ik0 = invk[lr], ik1 = invk[16+lr], ik2 = invk[32+lr];
    #pragma unroll
    for (int r=0;r<4;++r){
      const int row = ti*16 + lg*4 + r;
      const float iq = invq[row];
      float l0 = c3[0][r]*iq*ik0, l1 = c3[1][r]*iq*ik1, l2 = c3[2][r]*iq*ik2;
      float m = fmaxf(fmaxf(l0,l1),l2);
      m = fmaxf(m, __shfl_xor(m,1)); m = fmaxf(m, __shfl_xor(m,2));
      m = fmaxf(m, __shfl_xor(m,4)); m = fmaxf(m, __shfl_xor(m,8));
      float e0 = __expf(l0-m), e1 = __expf(l1-m), e2 = __expf(l2-m);
      float s = e0+e1+e2;
      s += __shfl_xor(s,1); s += __shfl_xor(s,2);
      s += __shfl_xor(s,4); s += __shfl_xor(s,8);
      const float is = 1.f / s;
      p_s[swz(row, lr)]    = f2bf(e0*is);
      p_s[swz(row, 16+lr)] = f2bf(e1*is);
      p_s[swz(row, 32+lr)] = f2bf(e2*is);
    }
  }
  __syncthreads();

  // O = P v -> NHWC ao[b][p][h*48 + d]
  const int wy = win >> 5, wx = win & 31;
  u16* ab = aout + (size_t)b*HW*CC + (size_t)h*DD;
  for (int t = wv; t < 12; t += 4){
    int ti = t >> 2, tj = t & 3;
    f32x4 c = {0.f,0.f,0.f,0.f};
    #pragma unroll
    for (int ks=0; ks<2; ++ks){
      bf16x8 a  = *(const bf16x8*)(p_s + swz(ti*16+lr, ks*32 + lg*8));
      bf16x8 bb = *(const bf16x8*)(v_t + swz(tj*16+lr, ks*32 + lg*8));
      c = __builtin_amdgcn_mfma_f32_16x16x32_bf16(a, bb, c, 0,0,0);
    }
    int scol = tj*16 + lr;
    if (scol < SS){
      int pi = scol / PSZ, pj = scol - pi*PSZ;
      size_t p = (size_t)(wy*PSZ + pi)*WW2 + wx*PSZ + pj;
      u32 lo = (u32)f2bf(c[0]) | ((u32)f2bf(c[1]) << 16);
      u32 hi = (u32)f2bf(c[2]) | ((u32)f2bf(c[3]) << 16);
      u32* dst = (u32*)(ab + p*CC + ti*16 + lg*4);   // 8-B aligned
      dst[0] = lo; dst[1] = hi;
    }
  }
}

// ---------------- launch ----------------
extern "C" void kernel_launch(void* const* d_in, const int* in_sizes, int n_in,
                              void* d_out, int out_size, void* d_ws, size_t ws_size,
                              hipStream_t stream) {
  const float* x     = (const float*)d_in[0];
  const float* qkvw  = (const float*)d_in[1];
  const float* dww   = (const float*)d_in[2];
  const float* temp  = (const float*)d_in[3];
  const float* projw = (const float*)d_in[4];
  float* out = (float*)d_out;

  // ws layout (bytes); xt aliases qkv2 region (dead before k_dw writes);
  // ao aliases qkv (dead after k_dw reads).
  const size_t SZ_QKV   = (size_t)NB*C3*HW*2;            // 231,211,008
  const size_t SZ_QKV2  = (size_t)NB*C3*NWINS*SSP*2;     // 235,929,600
  const size_t OFF_QKV2 = SZ_QKV;
  const size_t OFF_W1   = OFF_QKV2 + SZ_QKV2;            // 467,140,608
  const size_t OFF_W2   = OFF_W1 + (size_t)C3*CC*2;
  const size_t NEEDED   = OFF_W2 + (size_t)CC*CC*2;      // 468,320,256

  if (ws_size < NEEDED){
    k_sentinel<<<(out_size + 255)/256, 256, 0, stream>>>(out, out_size);
    return;
  }
  char* ws = (char*)d_ws;
  u16* qkv  = (u16*)ws;
  u16* qkv2 = (u16*)(ws + OFF_QKV2);
  u16* xt   = (u16*)(ws + OFF_QKV2);    // aliases qkv2 (xt dead before k_dw)
  u16* ao   = (u16*)ws;                 // aliases qkv
  u16* qwb  = (u16*)(ws + OFF_W1);
  u16* pwb  = (u16*)(ws + OFF_W2);

  k_cvt<<<dim3((C3*CC)/256), 256, 0, stream>>>(qkvw, projw, qwb, pwb);
  k_trx<<<dim3(784, NB), 256, 0, stream>>>(x, xt);
  k_gemm<0><<<dim3(9,392,2), 256, 0, stream>>>(qwb, xt, qkv);
  k_dw<<<dim3(32, C3/2, NB), 256, 0, stream>>>(qkv, dww, qkv2);
  k_attn<<<dim3(NHEADS, NWINS, NB), 256, 0, stream>>>(qkv2, temp, ao);
  k_gemm<1><<<dim3(3,392,2), 256, 0, stream>>>(pwb, ao, out);
}

// Round 8
// 547.830 us; speedup vs baseline: 4.0203x; 1.0540x over previous
//
#include <hip/hip_runtime.h>

// Channel attention (XCA windowed) for MI355X / gfx950.
// Shapes: b=2, C=384, H=W=224, heads=8, d=48, ps=7, nh=nw=32, windows=1024, s=49.
// Pipeline: [k_cvt] weights->bf16       [k_trx] x fp32 NCHW -> bf16 NHWC xt[b][p][c]
//           [k_gemm<0>] qkv 1x1 (MFMA, global_load_lds staging) -> bf16 NCHW
//           [k_dw] depthwise 3x3, column-stripe regs -> bf16 [b][o][win][50]
//           [k_attn] in-register softmax attention -> bf16 NHWC ao[b][p][c]
//           [k_gemm<1>] proj 1x1 -> fp32 NCHW d_out
// ws aliasing: xt overlays qkv2 region (dead before k_dw); ao overlays qkv.

#define NB     2
#define CC     384
#define C3     1152
#define HH     224
#define WW2    224
#define HW     50176
#define NHEADS 8
#define DD     48
#define PSZ    7
#define NWINS  1024
#define SS     49
#define SSP    50                 // padded record length (4-B alignment; slot 49 = 0)
#define WS50   (NWINS*SSP)        // 51200: per-channel stride in qkv2

typedef unsigned int  u32;
typedef unsigned short u16;
typedef __bf16 bf16x8 __attribute__((ext_vector_type(8)));
typedef float  f32x4  __attribute__((ext_vector_type(4)));

// native HW convert (v_cvt bf16, RNE) — manual bit-math was ~4 VALU/value
__device__ __forceinline__ u16 f2bf(float f){
  union { __bf16 h; u16 u; } v; v.h = (__bf16)f; return v.u;
}
__device__ __forceinline__ float bf2f(u16 h){
  union { u32 u; float f; } v; v.u = ((u32)h) << 16;
  return v.f;
}
__device__ __forceinline__ float u16lo(u32 u){   // low bf16 -> f32
  union { u32 u; float f; } v; v.u = u << 16; return v.f;
}
__device__ __forceinline__ float u16hi(u32 u){   // high bf16 -> f32
  union { u32 u; float f; } v; v.u = u & 0xffff0000u; return v.f;
}

// async global->LDS, 16 B per lane
typedef __attribute__((address_space(3))) u32 as3_u32;
typedef __attribute__((address_space(1))) const u32 as1_u32;
__device__ __forceinline__ void gld16(const void* g, void* l){
  __builtin_amdgcn_global_load_lds((as1_u32*)(unsigned long long)(g),
                                   (as3_u32*)(u32)(unsigned long long)(l),
                                   16, 0, 0);
}

// XOR swizzle for LDS tiles with 64-ushort (128 B) rows (attn tiles).
__device__ __forceinline__ int swz(int row, int col){
  return row*64 + (col ^ ((row & 7) << 3));
}

// ---------------- weight conversion ----------------
__global__ void k_cvt(const float* __restrict__ qw, const float* __restrict__ pw,
                      u16* __restrict__ qwb, u16* __restrict__ pwb){
  int i = blockIdx.x * 256 + threadIdx.x;
  if (i < C3*CC) qwb[i] = f2bf(qw[i]);
  if (i < CC*CC) pwb[i] = f2bf(pw[i]);
}

// ---------------- sentinel (ws too small) ----------------
__global__ void k_sentinel(float* __restrict__ out, int n){
  int i = blockIdx.x * 256 + threadIdx.x;
  if (i < n) out[i] = 12345.0f;
}

// ---------------- x transpose+convert: NCHW fp32 -> NHWC bf16 ----------------
#define CPAD 386
__global__ __launch_bounds__(256) void k_trx(const float* __restrict__ x,
                                             u16* __restrict__ xt){
  const int pt = blockIdx.x, b = blockIdx.y, tid = threadIdx.x;
  __shared__ u16 t[64*CPAD];
  const float* xb = x + (size_t)b*CC*HW + pt*64;
  #pragma unroll
  for (int it=0; it<24; ++it){
    int i = tid + it*256;
    int c = i >> 4, p4 = (i & 15)*4;
    float4 v = *(const float4*)(xb + (size_t)c*HW + p4);
    t[(p4+0)*CPAD + c] = f2bf(v.x);
    t[(p4+1)*CPAD + c] = f2bf(v.y);
    t[(p4+2)*CPAD + c] = f2bf(v.z);
    t[(p4+3)*CPAD + c] = f2bf(v.w);
  }
  __syncthreads();
  u32* dst = (u32*)(xt + ((size_t)b*HW + (size_t)pt*64)*CC);
  #pragma unroll
  for (int it=0; it<48; ++it){
    int j = tid + it*256;
    int p = j / 192, c2 = j - p*192;
    dst[j] = *(const u32*)(t + p*CPAD + c2*2);
  }
}

// ---------------- 1x1-conv GEMM (symmetric bf16 staging) ----------------
template<int OUT_F32>
__global__ __launch_bounds__(256) void k_gemm(const u16* __restrict__ A,
    const u16* __restrict__ B, void* __restrict__ Cdst){
  __shared__ __align__(16) u16 As[128*32];   // [m][k]
  __shared__ __align__(16) u16 Bs[128*32];   // [n][k]
  const int m0 = blockIdx.x * 128, n0 = blockIdx.y * 128, b = blockIdx.z;
  const int M  = gridDim.x * 128;
  const int tid = threadIdx.x, lane = tid & 63, wv = tid >> 6;
  const int wm = (wv & 1) * 64, wn = (wv >> 1) * 64;
  const int lr = lane & 15, lg = lane >> 4;
  const u16* Bb = B + (size_t)b*HW*CC;

  f32x4 acc[4][4];
  #pragma unroll
  for (int i=0;i<4;++i)
    #pragma unroll
    for (int j=0;j<4;++j) acc[i][j] = {0.f,0.f,0.f,0.f};

  for (int kk=0; kk<12; ++kk){
    const int k0 = kk*32;
    __syncthreads();
    #pragma unroll
    for (int i=0;i<2;++i){
      int chunk = i*256 + tid;
      int row = chunk >> 2, c4 = chunk & 3;
      gld16(A  + (size_t)(m0+row)*CC + k0 + c4*8, As + chunk*8);
      gld16(Bb + (size_t)(n0+row)*CC + k0 + c4*8, Bs + chunk*8);
    }
    __syncthreads();
    bf16x8 af[4], bfr[4];
    #pragma unroll
    for (int i=0;i<4;++i) af[i]  = *(const bf16x8*)(As + (wm + i*16 + lr)*32 + lg*8);
    #pragma unroll
    for (int j=0;j<4;++j) bfr[j] = *(const bf16x8*)(Bs + (wn + j*16 + lr)*32 + lg*8);
    #pragma unroll
    for (int i=0;i<4;++i)
      #pragma unroll
      for (int j=0;j<4;++j)
        acc[i][j] = __builtin_amdgcn_mfma_f32_16x16x32_bf16(af[i], bfr[j], acc[i][j], 0, 0, 0);
  }
  #pragma unroll
  for (int i=0;i<4;++i){
    #pragma unroll
    for (int j=0;j<4;++j){
      const int row = m0 + wm + i*16 + lg*4;
      const int col = n0 + wn + j*16 + lr;
      if (OUT_F32){
        float* Cp = (float*)Cdst + (size_t)b*M*HW;
        #pragma unroll
        for (int r=0;r<4;++r) Cp[(size_t)(row+r)*HW + col] = acc[i][j][r];
      } else {
        u16* Cp = (u16*)Cdst + (size_t)b*M*HW;
        #pragma unroll
        for (int r=0;r<4;++r) Cp[(size_t)(row+r)*HW + col] = f2bf(acc[i][j][r]);
      }
    }
  }
}

// ---------------- depthwise 3x3, SAME — column-stripe register version ----------------
// v3: block = (wy, 4ch, b) x 128 threads; thread = (ch, wx) computes the full
// 7x7 window column, sliding 3 register tap-rows over 9 LDS rows.
// Round-7 bug: copy-out used 100 uint4/channel; correct is 200 (32 rec x 50 u16
// = 1600 u16 = 200 uint4) -> windows wx>=16 kept stale bytes. Fixed to 800 total.
#define DWL 240    // lds row length in u16: 8 pad | 224 data | halo slot 232 | spare
__global__ __launch_bounds__(128) void k_dw(const u16* __restrict__ qkv,
    const float* __restrict__ dww, u16* __restrict__ qkv2){
  const int wy = blockIdx.x, o0 = blockIdx.y*4, b = blockIdx.z;
  const int tid = threadIdx.x;
  __shared__ __align__(16) u16 lin[4*9*DWL];     // 8640 u16
  __shared__ __align__(16) u16 outb[4*32*SSP];   // 6400 u16

  const int y0 = wy*PSZ - 1;

  // halo-col zeros: x=-1 -> idx 7, x=224 -> idx 232
  if (tid < 72){
    int ch = tid/18, rem = tid%18, r = rem>>1;
    lin[ch*9*DWL + r*DWL + ((rem&1) ? 232 : 7)] = 0;
  }
  // pad slot 49 of each of the 128 records
  outb[tid*SSP + 49] = 0;

  // stage: 4ch x 9rows x 28 uint4 (224 u16/row), OOB rows write zeros
  #pragma unroll
  for (int it=0; it<8; ++it){
    int i = tid + it*128;
    if (i < 1008){
      int ch = i / 252, rem = i - ch*252;
      int r = rem / 28, c16 = rem - r*28;
      int y = y0 + r;
      uint4 v = {0,0,0,0};
      if (y >= 0 && y < HH)
        v = *(const uint4*)(qkv + (size_t)(b*C3 + o0 + ch)*HW + (size_t)y*WW2 + c16*8);
      *(uint4*)(lin + ch*9*DWL + r*DWL + 8 + c16*8) = v;
    }
  }
  __syncthreads();

  // compute: thread = (ch, wx); taps for row r: lds idx (xb+7)+c, c=0..8
  {
    const int ch = tid >> 5, wx = tid & 31;
    const u16* L = lin + ch*9*DWL;
    const int xb = wx*PSZ;
    const int s0 = (xb+7) & ~1;
    const bool par = (xb+7) & 1;

    float wk[9];
    #pragma unroll
    for (int i=0;i<9;++i) wk[i] = dww[(o0+ch)*9 + i];

    float tr[3][9];
    // row loader: 5 ds_read_b32 + 10 unpack + 9 cndmask
    #define LOADROW(slot, r) {                                   \
      u32 u0 = *(const u32*)(L + (r)*DWL + s0);                  \
      u32 u1 = *(const u32*)(L + (r)*DWL + s0 + 2);              \
      u32 u2 = *(const u32*)(L + (r)*DWL + s0 + 4);              \
      u32 u3 = *(const u32*)(L + (r)*DWL + s0 + 6);              \
      u32 u4 = *(const u32*)(L + (r)*DWL + s0 + 8);              \
      float a0=u16lo(u0),a1=u16hi(u0),a2=u16lo(u1),a3=u16hi(u1); \
      float a4=u16lo(u2),a5=u16hi(u2),a6=u16lo(u3),a7=u16hi(u3); \
      float a8=u16lo(u4),a9=u16hi(u4);                           \
      tr[slot][0]=par?a1:a0; tr[slot][1]=par?a2:a1;              \
      tr[slot][2]=par?a3:a2; tr[slot][3]=par?a4:a3;              \
      tr[slot][4]=par?a5:a4; tr[slot][5]=par?a6:a5;              \
      tr[slot][6]=par?a7:a6; tr[slot][7]=par?a8:a7;              \
      tr[slot][8]=par?a9:a8; }

    LOADROW(0, 0)
    LOADROW(1, 1)

    u32 pk[24];           // 48 bf16 outputs packed; #48 kept separate
    u16 last;
    #pragma unroll
    for (int pi=0; pi<7; ++pi){
      LOADROW((pi+2)%3, pi+2)
      const float* r0 = tr[pi%3];
      const float* r1 = tr[(pi+1)%3];
      const float* r2 = tr[(pi+2)%3];
      float o[7];
      #pragma unroll
      for (int pj=0; pj<7; ++pj){
        float s = 0.f;
        #pragma unroll
        for (int kx=0;kx<3;++kx){
          s += wk[kx]  *r0[pj+kx];
          s += wk[3+kx]*r1[pj+kx];
          s += wk[6+kx]*r2[pj+kx];
        }
        o[pj] = s;
      }
      #pragma unroll
      for (int pj=0; pj<7; ++pj){
        int idx = pi*7 + pj;
        u16 bv = f2bf(o[pj]);
        if (idx == 48){ last = bv; }
        else {
          if ((idx & 1) == 0) pk[idx>>1] = (u32)bv;
          else                pk[idx>>1] |= ((u32)bv) << 16;
        }
      }
    }
    u16* rec = outb + tid*SSP;       // (ch*32+wx)*50
    #pragma unroll
    for (int i=0;i<24;++i) *(u32*)(rec + 2*i) = pk[i];
    rec[48] = last;
  }
  __syncthreads();

  // copy-out: per channel 32 records x 50 u16 = 3200 B = 200 uint4; 800 total
  #pragma unroll
  for (int it=0; it<7; ++it){
    int i = tid + it*128;
    if (i < 800){
      int ch = i / 200, idx = i - ch*200;
      u16* dst = qkv2 + ((size_t)(b*C3 + o0 + ch)*NWINS + (size_t)wy*32)*SSP;
      *(uint4*)(dst + idx*8) = *(const uint4*)(outb + ch*32*SSP + idx*8);
    }
  }
}

// ---------------- windowed channel attention ----------------
__global__ __launch_bounds__(256) void k_attn(const u16* __restrict__ qkv2,
    const float* __restrict__ temp, u16* __restrict__ aout){
  const int h = blockIdx.x, win = blockIdx.y, b = blockIdx.z;
  const int tid = threadIdx.x, lane = tid & 63, wv = tid >> 6;
  const int lr = lane & 15, lg = lane >> 4;

  __shared__ __align__(16) u16 q_s[48*64], k_s[48*64], v_t[64*64], p_s[48*64];
  __shared__ float invq[48], invk[48];

  for (int i=tid; i<48*32; i+=256){ ((u32*)q_s)[i]=0u; ((u32*)k_s)[i]=0u; ((u32*)p_s)[i]=0u; }
  for (int i=tid; i<64*32; i+=256) ((u32*)v_t)[i]=0u;
  __syncthreads();

  const u16* qsrc = qkv2 + ((size_t)(b*C3 +        h*DD)*NWINS + win)*SSP;
  const u16* ksrc = qkv2 + ((size_t)(b*C3 + CC   + h*DD)*NWINS + win)*SSP;
  const u16* vsrc = qkv2 + ((size_t)(b*C3 + 2*CC + h*DD)*NWINS + win)*SSP;
  for (int i=tid; i<48*25; i+=256){
    int dc = i / 25, c = i - dc*25;
    size_t off = (size_t)dc*WS50 + 2*c;
    u32 vq = *(const u32*)(qsrc + off);
    u32 vk = *(const u32*)(ksrc + off);
    u32 vv = *(const u32*)(vsrc + off);
    int sw = swz(dc, 2*c);
    *(u32*)(q_s + sw) = vq;
    *(u32*)(k_s + sw) = vk;
    v_t[swz(2*c,   dc)] = (u16)(vv & 0xffffu);
    v_t[swz(2*c+1, dc)] = (u16)(vv >> 16);
  }
  __syncthreads();

  if (tid < 192){
    const int row96 = tid >> 1, half = tid & 1;
    const int rr = (row96 < 48) ? row96 : row96 - 48;
    const u16* a = (row96 < 48) ? q_s : k_s;
    const int s0 = half ? 25 : 0, s1 = half ? 49 : 25;
    float sum = 0.f;
    for (int s=s0; s<s1; ++s){ float v = bf2f(a[swz(rr,s)]); sum += v*v; }
    sum += __shfl_xor(sum, 1);
    if (!half){
      float inv = 1.f / fmaxf(sqrtf(sum), 1e-12f);
      if (row96 < 48) invq[rr] = inv * temp[h]; else invk[rr] = inv;
    }
  }
  __syncthreads();

  if (wv < 3){
    const int ti = wv;
    f32x4 c3[3];
    #pragma unroll
    for (int tj=0;tj<3;++tj) c3[tj] = {0.f,0.f,0.f,0.f};
    #pragma unroll
    for (int tj=0;tj<3;++tj){
      #pragma unroll
      for (int ks=0; ks<2; ++ks){
        bf16x8 a  = *(const bf16x8*)(q_s + swz(ti*16+lr, ks*32 + lg*8));
        bf16x8 bb = *(const bf16x8*)(k_s + swz(tj*16+lr, ks*32 + lg*8));
        c3[tj] = __builtin_amdgcn_mfma_f32_16x16x32_bf16(a, bb, c3[tj], 0,0,0);
      }
    }
    const float ik0 = invk[lr], ik1 = invk[16+lr], ik2 = invk[32+lr];
    #pragma unroll
    for (int r=0;r<4;++r){
      const int row = ti*16 + lg*4 + r;
      const float iq = invq[row];
      float l0 = c3[0][r]*iq*ik0, l1 = c3[1][r]*iq*ik1, l2 = c3[2][r]*iq*ik2;
      float m = fmaxf(fmaxf(l0,l1),l2);
      m = fmaxf(m, __shfl_xor(m,1)); m = fmaxf(m, __shfl_xor(m,2));
      m = fmaxf(m, __shfl_xor(m,4)); m = fmaxf(m, __shfl_xor(m,8));
      float e0 = __expf(l0-m), e1 = __expf(l1-m), e2 = __expf(l2-m);
      float s = e0+e1+e2;
      s += __shfl_xor(s,1); s += __shfl_xor(s,2);
      s += __shfl_xor(s,4); s += __shfl_xor(s,8);
      const float is = 1.f / s;
      p_s[swz(row, lr)]    = f2bf(e0*is);
      p_s[swz(row, 16+lr)] = f2bf(e1*is);
      p_s[swz(row, 32+lr)] = f2bf(e2*is);
    }
  }
  __syncthreads();

  const int wy = win >> 5, wx = win & 31;
  u16* ab = aout + (size_t)b*HW*CC + (size_t)h*DD;
  for (int t = wv; t < 12; t += 4){
    int ti = t >> 2, tj = t & 3;
    f32x4 c = {0.f,0.f,0.f,0.f};
    #pragma unroll
    for (int ks=0; ks<2; ++ks){
      bf16x8 a  = *(const bf16x8*)(p_s + swz(ti*16+lr, ks*32 + lg*8));
      bf16x8 bb = *(const bf16x8*)(v_t + swz(tj*16+lr, ks*32 + lg*8));
      c = __builtin_amdgcn_mfma_f32_16x16x32_bf16(a, bb, c, 0,0,0);
    }
    int scol = tj*16 + lr;
    if (scol < SS){
      int pi = scol / PSZ, pj = scol - pi*PSZ;
      size_t p = (size_t)(wy*PSZ + pi)*WW2 + wx*PSZ + pj;
      u32 lo = (u32)f2bf(c[0]) | ((u32)f2bf(c[1]) << 16);
      u32 hi = (u32)f2bf(c[2]) | ((u32)f2bf(c[3]) << 16);
      u32* dst = (u32*)(ab + p*CC + ti*16 + lg*4);
      dst[0] = lo; dst[1] = hi;
    }
  }
}

// ---------------- launch ----------------
extern "C" void kernel_launch(void* const* d_in, const int* in_sizes, int n_in,
                              void* d_out, int out_size, void* d_ws, size_t ws_size,
                              hipStream_t stream) {
  const float* x     = (const float*)d_in[0];
  const float* qkvw  = (const float*)d_in[1];
  const float* dww   = (const float*)d_in[2];
  const float* temp  = (const float*)d_in[3];
  const float* projw = (const float*)d_in[4];
  float* out = (float*)d_out;

  const size_t SZ_QKV   = (size_t)NB*C3*HW*2;            // 231,211,008
  const size_t SZ_QKV2  = (size_t)NB*C3*NWINS*SSP*2;     // 235,929,600
  const size_t OFF_QKV2 = SZ_QKV;
  const size_t OFF_W1   = OFF_QKV2 + SZ_QKV2;            // 467,140,608
  const size_t OFF_W2   = OFF_W1 + (size_t)C3*CC*2;
  const size_t NEEDED   = OFF_W2 + (size_t)CC*CC*2;      // 468,320,256

  if (ws_size < NEEDED){
    k_sentinel<<<(out_size + 255)/256, 256, 0, stream>>>(out, out_size);
    return;
  }
  char* ws = (char*)d_ws;
  u16* qkv  = (u16*)ws;
  u16* qkv2 = (u16*)(ws + OFF_QKV2);
  u16* xt   = (u16*)(ws + OFF_QKV2);    // aliases qkv2 (xt dead before k_dw)
  u16* ao   = (u16*)ws;                 // aliases qkv
  u16* qwb  = (u16*)(ws + OFF_W1);
  u16* pwb  = (u16*)(ws + OFF_W2);

  k_cvt<<<dim3((C3*CC)/256), 256, 0, stream>>>(qkvw, projw, qwb, pwb);
  k_trx<<<dim3(784, NB), 256, 0, stream>>>(x, xt);
  k_gemm<0><<<dim3(9,392,2), 256, 0, stream>>>(qwb, xt, qkv);
  k_dw<<<dim3(32, C3/4, NB), 128, 0, stream>>>(qkv, dww, qkv2);
  k_attn<<<dim3(NHEADS, NWINS, NB), 256, 0, stream>>>(qkv2, temp, ao);
  k_gemm<1><<<dim3(3,392,2), 256, 0, stream>>>(pwb, ao, out);
}